// Round 1
// baseline (3317.247 us; speedup 1.0000x reference)
//
#include <hip/hip_runtime.h>
#include <hip/hip_bf16.h>

// Problem constants
#define Bn 4
#define Hn 512
#define Wn 512
#define Cn 16
#define Sn 10
#define HWn (Hn*Wn)          // 262144 = 1<<18
#define BHW (Bn*HWn)         // 1048576

// ---------------- conv0: 1->16, 3x3, pad 1, bias ----------------
__global__ void k_conv0(const float* __restrict__ photos, const float* __restrict__ w0,
                        const float* __restrict__ b0, float* __restrict__ out) {
    __shared__ float sw[Cn*9];
    __shared__ float sb[Cn];
    int t = threadIdx.x;
    if (t < Cn*9) sw[t] = w0[t];
    if (t < Cn)   sb[t] = b0[t];
    __syncthreads();
    int idx = blockIdx.x * blockDim.x + t;
    if (idx >= BHW) return;
    int w = idx & 511, h = (idx >> 9) & 511, b = idx >> 18;
    const float* pb = photos + (b << 18);
    float patch[9];
    #pragma unroll
    for (int dy = -1; dy <= 1; ++dy) {
        #pragma unroll
        for (int dx = -1; dx <= 1; ++dx) {
            int hh = h + dy, ww = w + dx;
            float v = 0.f;
            if ((unsigned)hh < 512u && (unsigned)ww < 512u) v = pb[(hh << 9) + ww];
            patch[(dy + 1) * 3 + (dx + 1)] = v;
        }
    }
    #pragma unroll
    for (int c = 0; c < Cn; ++c) {
        float acc = sb[c];
        #pragma unroll
        for (int k = 0; k < 9; ++k) acc += patch[k] * sw[c * 9 + k];
        out[((b * Cn + c) << 18) + (h << 9) + w] = acc;
    }
}

// ---------------- inverted residual: dw3x3 + bn + relu6 + pw1x1 + bn + skip ----------------
__global__ void k_ir(const float* __restrict__ x, float* __restrict__ y,
                     const float* __restrict__ dww, const float* __restrict__ as_,
                     const float* __restrict__ ab_, const float* __restrict__ pww,
                     const float* __restrict__ bs_, const float* __restrict__ bb_) {
    __shared__ float sdw[Cn*9], spw[Cn*Cn], sas[Cn], sab[Cn], sbs[Cn], sbb[Cn];
    int t = threadIdx.x;
    if (t < Cn*9)  sdw[t] = dww[t];
    if (t < Cn*Cn) spw[t] = pww[t];
    if (t < Cn) { sas[t] = as_[t]; sab[t] = ab_[t]; sbs[t] = bs_[t]; sbb[t] = bb_[t]; }
    __syncthreads();
    int idx = blockIdx.x * blockDim.x + t;
    if (idx >= BHW) return;
    int w = idx & 511, h = (idx >> 9) & 511, b = idx >> 18;
    float tm[Cn];
    #pragma unroll
    for (int c = 0; c < Cn; ++c) {
        const float* xb = x + ((b * Cn + c) << 18);
        float acc = 0.f;
        #pragma unroll
        for (int dy = -1; dy <= 1; ++dy) {
            int hh = h + dy;
            if ((unsigned)hh >= 512u) continue;
            #pragma unroll
            for (int dx = -1; dx <= 1; ++dx) {
                int ww = w + dx;
                if ((unsigned)ww >= 512u) continue;
                acc += xb[(hh << 9) + ww] * sdw[c * 9 + (dy + 1) * 3 + (dx + 1)];
            }
        }
        float v = acc * sas[c] + sab[c];
        tm[c] = fminf(fmaxf(v, 0.f), 6.f);
    }
    #pragma unroll
    for (int o = 0; o < Cn; ++o) {
        float acc = 0.f;
        #pragma unroll
        for (int i = 0; i < Cn; ++i) acc += tm[i] * spw[o * Cn + i];
        float v = acc * sbs[o] + sbb[o];
        int oi = ((b * Cn + o) << 18) + (h << 9) + w;
        y[oi] = x[oi] + v;
    }
}

// ---------------- score conv: 16->10, 3x3, pad 1, bias ----------------
__global__ void k_convs(const float* __restrict__ x, const float* __restrict__ wsw,
                        const float* __restrict__ bsv, float* __restrict__ s) {
    __shared__ float sw[Sn*Cn*9]; // 1440
    __shared__ float sb[Sn];
    int t = threadIdx.x;
    for (int i = t; i < Sn*Cn*9; i += blockDim.x) sw[i] = wsw[i];
    if (t < Sn) sb[t] = bsv[t];
    __syncthreads();
    int idx = blockIdx.x * blockDim.x + t;
    if (idx >= BHW) return;
    int w = idx & 511, h = (idx >> 9) & 511, b = idx >> 18;
    float acc[Sn];
    #pragma unroll
    for (int o = 0; o < Sn; ++o) acc[o] = sb[o];
    #pragma unroll
    for (int c = 0; c < Cn; ++c) {
        const float* xb = x + ((b * Cn + c) << 18);
        float patch[9];
        #pragma unroll
        for (int dy = -1; dy <= 1; ++dy) {
            #pragma unroll
            for (int dx = -1; dx <= 1; ++dx) {
                int hh = h + dy, ww = w + dx;
                float v = 0.f;
                if ((unsigned)hh < 512u && (unsigned)ww < 512u) v = xb[(hh << 9) + ww];
                patch[(dy + 1) * 3 + (dx + 1)] = v;
            }
        }
        #pragma unroll
        for (int o = 0; o < Sn; ++o) {
            const float* wk = &sw[(o * Cn + c) * 9];
            float a = acc[o];
            #pragma unroll
            for (int k = 0; k < 9; ++k) a += patch[k] * wk[k];
            acc[o] = a;
        }
    }
    #pragma unroll
    for (int o = 0; o < Sn; ++o) s[((b * Sn + o) << 18) + (h << 9) + w] = acc[o];
}

// ---------------- instance norm: per-(b,c) stats ----------------
__global__ void k_in_stats(const float* __restrict__ s, float* __restrict__ stats) {
    int bc = blockIdx.x; // 0..39
    const float* p = s + ((size_t)bc << 18);
    double sum = 0.0, sq = 0.0;
    for (int i = threadIdx.x; i < HWn; i += blockDim.x) {
        double v = (double)p[i];
        sum += v; sq += v * v;
    }
    __shared__ double ssum[256], ssq[256];
    ssum[threadIdx.x] = sum; ssq[threadIdx.x] = sq;
    __syncthreads();
    for (int off = 128; off > 0; off >>= 1) {
        if (threadIdx.x < off) {
            ssum[threadIdx.x] += ssum[threadIdx.x + off];
            ssq[threadIdx.x]  += ssq[threadIdx.x + off];
        }
        __syncthreads();
    }
    if (threadIdx.x == 0) {
        double mu = ssum[0] / (double)HWn;
        double var = ssq[0] / (double)HWn - mu * mu;
        stats[bc * 2]     = (float)mu;
        stats[bc * 2 + 1] = rsqrtf((float)var + 1e-5f);
    }
}

__global__ void k_in_norm(float* __restrict__ s, const float* __restrict__ stats) {
    int idx = blockIdx.x * blockDim.x + threadIdx.x;
    if (idx >= Bn * Sn * HWn) return;
    int bc = idx >> 18;
    float mu = stats[bc * 2], rs = stats[bc * 2 + 1];
    float v = (s[idx] - mu) * rs;
    s[idx] = v >= 0.f ? v : 0.01f * v;
}

// ---------------- NMS stage ----------------
__global__ void k_chanmax(const float* __restrict__ s, float* __restrict__ m0) {
    int idx = blockIdx.x * blockDim.x + threadIdx.x;
    if (idx >= BHW) return;
    int b = idx >> 18, hw = idx & (HWn - 1);
    const float* p = s + ((b * Sn) << 18) + hw;
    float mx = p[0];
    #pragma unroll
    for (int c = 1; c < Sn; ++c) mx = fmaxf(mx, p[c << 18]);
    m0[idx] = mx;
}

__global__ void k_rowmax(const float* __restrict__ in, float* __restrict__ out) {
    int idx = blockIdx.x * blockDim.x + threadIdx.x;
    if (idx >= BHW) return;
    int w = idx & 511;
    int base = idx - w;
    int lo = max(w - 7, 0), hi = min(w + 7, 511);
    float mx = -INFINITY;
    for (int ww = lo; ww <= hi; ++ww) mx = fmaxf(mx, in[base + ww]);
    out[idx] = mx;
}

__global__ void k_colmax(const float* __restrict__ in, float* __restrict__ out) {
    int idx = blockIdx.x * blockDim.x + threadIdx.x;
    if (idx >= BHW) return;
    int w = idx & 511, h = (idx >> 9) & 511, b = idx >> 18;
    int lo = max(h - 7, 0), hi = min(h + 7, 511);
    float mx = -INFINITY;
    for (int hh = lo; hh <= hi; ++hh) mx = fmaxf(mx, in[(b << 18) + (hh << 9) + w]);
    out[idx] = mx;
}

__global__ void k_expsum(const float* __restrict__ s, const float* __restrict__ m,
                         float* __restrict__ es) {
    int idx = blockIdx.x * blockDim.x + threadIdx.x;
    if (idx >= BHW) return;
    int b = idx >> 18, hw = idx & (HWn - 1);
    const float* p = s + ((b * Sn) << 18) + hw;
    float mm = m[idx];
    float acc = 0.f;
    #pragma unroll
    for (int c = 0; c < Sn; ++c) acc += __expf(7.f * (p[c << 18] - mm));
    es[idx] = acc;
}

__global__ void k_rowsum(const float* __restrict__ in, float* __restrict__ out) {
    int idx = blockIdx.x * blockDim.x + threadIdx.x;
    if (idx >= BHW) return;
    int w = idx & 511;
    int base = idx - w;
    int lo = max(w - 7, 0), hi = min(w + 7, 511);
    float acc = 0.f;
    for (int ww = lo; ww <= hi; ++ww) acc += in[base + ww];
    out[idx] = acc;
}

__global__ void k_colsum(const float* __restrict__ in, float* __restrict__ out) {
    int idx = blockIdx.x * blockDim.x + threadIdx.x;
    if (idx >= BHW) return;
    int w = idx & 511, h = (idx >> 9) & 511, b = idx >> 18;
    int lo = max(h - 7, 0), hi = min(h + 7, 511);
    float acc = 0.f;
    for (int hh = lo; hh <= hi; ++hh) acc += in[(b << 18) + (hh << 9) + w];
    out[idx] = acc;
}

// ---------------- final channel softmax + outputs ----------------
__global__ void k_final(const float* __restrict__ s, const float* __restrict__ m,
                        const float* __restrict__ sume, const float* __restrict__ scl,
                        float* __restrict__ out) {
    __shared__ float sscale[Sn];
    if (threadIdx.x < Sn) sscale[threadIdx.x] = scl[threadIdx.x];
    __syncthreads();
    int idx = blockIdx.x * blockDim.x + threadIdx.x;
    if (idx >= BHW) return;
    int b = idx >> 18, hw = idx & (HWn - 1);
    const float* p = s + ((b * Sn) << 18) + hw;
    float mm = m[idx];
    float denom = sume[idx] + 1e-8f;
    float probs[Sn];
    float mx = -INFINITY;
    #pragma unroll
    for (int c = 0; c < Sn; ++c) {
        float pr = expf(7.f * (p[c << 18] - mm)) / denom;
        probs[c] = pr;
        mx = fmaxf(mx, pr);
    }
    float e1[Sn]; float d1 = 0.f;
    #pragma unroll
    for (int c = 0; c < Sn; ++c) { e1[c] = expf(100.f * (probs[c] - mx)); d1 += e1[c]; }
    float inv = 1.f / (d1 + 1e-8f);
    float score = 0.f, scale = 0.f;
    #pragma unroll
    for (int c = 0; c < Sn; ++c) {
        float p1 = e1[c] * inv;
        score += probs[c] * p1;
        scale += sscale[c] * p1;
    }
    out[idx] = score;
    out[BHW + idx] = scale;
}

extern "C" void kernel_launch(void* const* d_in, const int* in_sizes, int n_in,
                              void* d_out, int out_size, void* d_ws, size_t ws_size,
                              hipStream_t stream) {
    const float* photos = (const float*)d_in[0];
    const float* w0     = (const float*)d_in[1];
    const float* b0     = (const float*)d_in[2];
    const float* dw1_w  = (const float*)d_in[3];
    const float* bn1a_s = (const float*)d_in[4];
    const float* bn1a_b = (const float*)d_in[5];
    const float* pw1_w  = (const float*)d_in[6];
    const float* bn1b_s = (const float*)d_in[7];
    const float* bn1b_b = (const float*)d_in[8];
    const float* dw2_w  = (const float*)d_in[9];
    const float* bn2a_s = (const float*)d_in[10];
    const float* bn2a_b = (const float*)d_in[11];
    const float* pw2_w  = (const float*)d_in[12];
    const float* bn2b_s = (const float*)d_in[13];
    const float* bn2b_b = (const float*)d_in[14];
    const float* ws_w   = (const float*)d_in[15];
    const float* bs_v   = (const float*)d_in[16];
    const float* scl    = (const float*)d_in[17];

    char* wsb = (char*)d_ws;
    float* A  = (float*)(wsb);                         // 64 MiB (B,16,H,W)
    float* Bb = (float*)(wsb + 67108864);              // 64 MiB (B,16,H,W)
    float* S  = (float*)(wsb + 134217728);             // 40 MiB (B,10,H,W)
    // small temporaries alias A (dead after k_convs) and Bb (dead after k_convs)
    float* stats = Bb;                                 // 80 floats
    float* M0 = A;                                     // 4 MiB each
    float* M1 = A + 1 * (1 << 20);
    float* M  = A + 2 * (1 << 20);
    float* ES = A + 3 * (1 << 20);
    float* T  = A + 4 * (1 << 20);
    float* SU = A + 5 * (1 << 20);

    dim3 blk(256);
    int gBHW = BHW / 256;            // 4096
    int gAll = (Bn * Sn * HWn) / 256; // 40960

    k_conv0<<<gBHW, blk, 0, stream>>>(photos, w0, b0, A);
    k_ir<<<gBHW, blk, 0, stream>>>(A, Bb, dw1_w, bn1a_s, bn1a_b, pw1_w, bn1b_s, bn1b_b);
    k_ir<<<gBHW, blk, 0, stream>>>(Bb, A, dw2_w, bn2a_s, bn2a_b, pw2_w, bn2b_s, bn2b_b);
    k_convs<<<gBHW, blk, 0, stream>>>(A, ws_w, bs_v, S);
    k_in_stats<<<Bn * Sn, blk, 0, stream>>>(S, stats);
    k_in_norm<<<gAll, blk, 0, stream>>>(S, stats);
    k_chanmax<<<gBHW, blk, 0, stream>>>(S, M0);
    k_rowmax<<<gBHW, blk, 0, stream>>>(M0, M1);
    k_colmax<<<gBHW, blk, 0, stream>>>(M1, M);
    k_expsum<<<gBHW, blk, 0, stream>>>(S, M, ES);
    k_rowsum<<<gBHW, blk, 0, stream>>>(ES, T);
    k_colsum<<<gBHW, blk, 0, stream>>>(T, SU);
    k_final<<<gBHW, blk, 0, stream>>>(S, M, SU, scl, (float*)d_out);
}

// Round 2
// 532.268 us; speedup vs baseline: 6.2323x; 6.2323x over previous
//
#include <hip/hip_runtime.h>
#include <hip/hip_bf16.h>

// Problem constants
#define Bn 4
#define Hn 512
#define Wn 512
#define Cn 16
#define Sn 10
#define HWn (Hn*Wn)          // 262144 = 1<<18
#define BHW (Bn*HWn)         // 1048576
#define NG (BHW/4)           // 262144 pixel-groups (4 pixels along W per thread)

// Load 6 consecutive row floats (w0-1 .. w0+4) with boundary zeros.
__device__ __forceinline__ void load_row6(const float* __restrict__ rp, bool valid,
                                          int w0, float* r) {
    if (valid) {
        float4 v = *reinterpret_cast<const float4*>(rp + w0);
        r[1] = v.x; r[2] = v.y; r[3] = v.z; r[4] = v.w;
        r[0] = (w0 > 0)   ? rp[w0 - 1] : 0.f;
        r[5] = (w0 < 508) ? rp[w0 + 4] : 0.f;
    } else {
        r[0] = r[1] = r[2] = r[3] = r[4] = r[5] = 0.f;
    }
}

// ---------------- conv0: 1->16, 3x3, pad 1, bias; 4 px/thread ----------------
__global__ __launch_bounds__(256) void k_conv0(const float* __restrict__ photos,
        const float* __restrict__ w0v, const float* __restrict__ b0,
        float* __restrict__ out) {
    __shared__ float wp[Cn*12];
    __shared__ float sb[Cn];
    int t = threadIdx.x;
    if (t < Cn*9) { int o = t / 9, k = t % 9; wp[o*12 + k] = w0v[t]; }
    if (t < Cn) sb[t] = b0[t];
    __syncthreads();
    int idx = blockIdx.x * 256 + t;
    int w0 = (idx & 127) << 2, h = (idx >> 7) & 511, b = idx >> 16;
    const float* pb = photos + (b << 18);
    float xr[3][6];
    #pragma unroll
    for (int dy = 0; dy < 3; ++dy) {
        int hh = h + dy - 1;
        load_row6(pb + (hh << 9), (unsigned)hh < 512u, w0, xr[dy]);
    }
    #pragma unroll
    for (int o = 0; o < Cn; ++o) {
        float4 wa = *(const float4*)&wp[o*12];
        float4 wb = *(const float4*)&wp[o*12 + 4];
        float wk8 = wp[o*12 + 8];
        float wk[9] = {wa.x, wa.y, wa.z, wa.w, wb.x, wb.y, wb.z, wb.w, wk8};
        float bv = sb[o];
        float a0 = bv, a1 = bv, a2 = bv, a3 = bv;
        #pragma unroll
        for (int dy = 0; dy < 3; ++dy)
            #pragma unroll
            for (int dx = 0; dx < 3; ++dx) {
                float wv = wk[dy*3 + dx];
                a0 += xr[dy][dx + 0] * wv;
                a1 += xr[dy][dx + 1] * wv;
                a2 += xr[dy][dx + 2] * wv;
                a3 += xr[dy][dx + 3] * wv;
            }
        float4 r; r.x = a0; r.y = a1; r.z = a2; r.w = a3;
        *reinterpret_cast<float4*>(out + ((b*Cn + o) << 18) + (h << 9) + w0) = r;
    }
}

// ---------------- inverted residual, fused dw+bn+relu6+pw+bn+skip; 4 px/thread ----
__global__ __launch_bounds__(256) void k_ir(const float* __restrict__ x,
        float* __restrict__ y, const float* __restrict__ dww,
        const float* __restrict__ as_, const float* __restrict__ ab_,
        const float* __restrict__ pww, const float* __restrict__ bs_,
        const float* __restrict__ bb_) {
    __shared__ float dwp[Cn*12];
    __shared__ float pwT[Cn*Cn];   // pwT[i*16+o] = pw[o][i]
    __shared__ float sas[Cn], sab[Cn], sbs[Cn], sbb[Cn];
    int t = threadIdx.x;
    if (t < Cn*9)  { int c = t / 9, k = t % 9; dwp[c*12 + k] = dww[t]; }
    if (t < Cn*Cn) { int o = t >> 4, i = t & 15; pwT[i*16 + o] = pww[t]; }
    if (t < Cn) { sas[t] = as_[t]; sab[t] = ab_[t]; sbs[t] = bs_[t]; sbb[t] = bb_[t]; }
    __syncthreads();
    int idx = blockIdx.x * 256 + t;
    int w0 = (idx & 127) << 2, h = (idx >> 7) & 511, b = idx >> 16;
    float acc[Cn][4];
    #pragma unroll
    for (int o = 0; o < Cn; ++o) { acc[o][0] = acc[o][1] = acc[o][2] = acc[o][3] = 0.f; }
    #pragma unroll 1
    for (int c = 0; c < Cn; ++c) {
        const float* xp = x + ((b*Cn + c) << 18);
        float xr[3][6];
        #pragma unroll
        for (int dy = 0; dy < 3; ++dy) {
            int hh = h + dy - 1;
            load_row6(xp + (hh << 9), (unsigned)hh < 512u, w0, xr[dy]);
        }
        float4 wa = *(const float4*)&dwp[c*12];
        float4 wb = *(const float4*)&dwp[c*12 + 4];
        float wk8 = dwp[c*12 + 8];
        float wk[9] = {wa.x, wa.y, wa.z, wa.w, wb.x, wb.y, wb.z, wb.w, wk8};
        float t0 = 0.f, t1 = 0.f, t2 = 0.f, t3 = 0.f;
        #pragma unroll
        for (int dy = 0; dy < 3; ++dy)
            #pragma unroll
            for (int dx = 0; dx < 3; ++dx) {
                float wv = wk[dy*3 + dx];
                t0 += xr[dy][dx + 0] * wv;
                t1 += xr[dy][dx + 1] * wv;
                t2 += xr[dy][dx + 2] * wv;
                t3 += xr[dy][dx + 3] * wv;
            }
        float sc = sas[c], sh = sab[c];
        t0 = fminf(fmaxf(t0*sc + sh, 0.f), 6.f);
        t1 = fminf(fmaxf(t1*sc + sh, 0.f), 6.f);
        t2 = fminf(fmaxf(t2*sc + sh, 0.f), 6.f);
        t3 = fminf(fmaxf(t3*sc + sh, 0.f), 6.f);
        #pragma unroll
        for (int o4 = 0; o4 < 4; ++o4) {
            float4 wq = *(const float4*)&pwT[c*16 + o4*4];
            acc[o4*4+0][0] += t0*wq.x; acc[o4*4+0][1] += t1*wq.x;
            acc[o4*4+0][2] += t2*wq.x; acc[o4*4+0][3] += t3*wq.x;
            acc[o4*4+1][0] += t0*wq.y; acc[o4*4+1][1] += t1*wq.y;
            acc[o4*4+1][2] += t2*wq.y; acc[o4*4+1][3] += t3*wq.y;
            acc[o4*4+2][0] += t0*wq.z; acc[o4*4+2][1] += t1*wq.z;
            acc[o4*4+2][2] += t2*wq.z; acc[o4*4+2][3] += t3*wq.z;
            acc[o4*4+3][0] += t0*wq.w; acc[o4*4+3][1] += t1*wq.w;
            acc[o4*4+3][2] += t2*wq.w; acc[o4*4+3][3] += t3*wq.w;
        }
    }
    #pragma unroll
    for (int o = 0; o < Cn; ++o) {
        const float* xo = x + ((b*Cn + o) << 18) + (h << 9) + w0;
        float4 xv = *(const float4*)xo;
        float sc = sbs[o], sh = sbb[o];
        float4 r;
        r.x = xv.x + acc[o][0]*sc + sh;
        r.y = xv.y + acc[o][1]*sc + sh;
        r.z = xv.z + acc[o][2]*sc + sh;
        r.w = xv.w + acc[o][3]*sc + sh;
        *reinterpret_cast<float4*>(y + ((b*Cn + o) << 18) + (h << 9) + w0) = r;
    }
}

// ---------------- score conv: 16->10, 3x3, pad 1, bias; 4 px/thread ----------------
__global__ __launch_bounds__(256) void k_convs(const float* __restrict__ x,
        const float* __restrict__ wsw, const float* __restrict__ bsv,
        float* __restrict__ s) {
    __shared__ float wp[Cn*Sn*12];   // wp[(c*10+o)*12+k]
    __shared__ float sb[Sn];
    int t = threadIdx.x;
    for (int i = t; i < Sn*Cn*9; i += 256) {
        int o = i / (Cn*9), r = i % (Cn*9), c = r / 9, k = r % 9;
        wp[(c*Sn + o)*12 + k] = wsw[i];
    }
    if (t < Sn) sb[t] = bsv[t];
    __syncthreads();
    int idx = blockIdx.x * 256 + t;
    int w0 = (idx & 127) << 2, h = (idx >> 7) & 511, b = idx >> 16;
    float acc[Sn][4];
    #pragma unroll
    for (int o = 0; o < Sn; ++o) {
        float bv = sb[o];
        acc[o][0] = bv; acc[o][1] = bv; acc[o][2] = bv; acc[o][3] = bv;
    }
    #pragma unroll 1
    for (int c = 0; c < Cn; ++c) {
        const float* xp = x + ((b*Cn + c) << 18);
        float xr[3][6];
        #pragma unroll
        for (int dy = 0; dy < 3; ++dy) {
            int hh = h + dy - 1;
            load_row6(xp + (hh << 9), (unsigned)hh < 512u, w0, xr[dy]);
        }
        #pragma unroll
        for (int o = 0; o < Sn; ++o) {
            const float* wb_ = &wp[(c*Sn + o)*12];
            float4 wa = *(const float4*)wb_;
            float4 wbv = *(const float4*)(wb_ + 4);
            float wk8 = wb_[8];
            float wk[9] = {wa.x, wa.y, wa.z, wa.w, wbv.x, wbv.y, wbv.z, wbv.w, wk8};
            #pragma unroll
            for (int dy = 0; dy < 3; ++dy)
                #pragma unroll
                for (int dx = 0; dx < 3; ++dx) {
                    float wv = wk[dy*3 + dx];
                    acc[o][0] += xr[dy][dx + 0] * wv;
                    acc[o][1] += xr[dy][dx + 1] * wv;
                    acc[o][2] += xr[dy][dx + 2] * wv;
                    acc[o][3] += xr[dy][dx + 3] * wv;
                }
        }
    }
    #pragma unroll
    for (int o = 0; o < Sn; ++o) {
        float4 r; r.x = acc[o][0]; r.y = acc[o][1]; r.z = acc[o][2]; r.w = acc[o][3];
        *reinterpret_cast<float4*>(s + ((b*Sn + o) << 18) + (h << 9) + w0) = r;
    }
}

// ---------------- instance norm: per-(b,c) stats ----------------
__global__ __launch_bounds__(256) void k_in_stats(const float* __restrict__ s,
                                                  float* __restrict__ stats) {
    int bc = blockIdx.x; // 0..39
    const float* p = s + ((size_t)bc << 18);
    double sum = 0.0, sq = 0.0;
    for (int i = threadIdx.x; i < HWn; i += blockDim.x) {
        double v = (double)p[i];
        sum += v; sq += v * v;
    }
    __shared__ double ssum[256], ssq[256];
    ssum[threadIdx.x] = sum; ssq[threadIdx.x] = sq;
    __syncthreads();
    for (int off = 128; off > 0; off >>= 1) {
        if (threadIdx.x < off) {
            ssum[threadIdx.x] += ssum[threadIdx.x + off];
            ssq[threadIdx.x]  += ssq[threadIdx.x + off];
        }
        __syncthreads();
    }
    if (threadIdx.x == 0) {
        double mu = ssum[0] / (double)HWn;
        double var = ssq[0] / (double)HWn - mu * mu;
        stats[bc * 2]     = (float)mu;
        stats[bc * 2 + 1] = rsqrtf((float)var + 1e-5f);
    }
}

__global__ __launch_bounds__(256) void k_in_norm(float* __restrict__ s,
                                                 const float* __restrict__ stats) {
    int idx = blockIdx.x * blockDim.x + threadIdx.x;
    if (idx >= Bn * Sn * HWn) return;
    int bc = idx >> 18;
    float mu = stats[bc * 2], rs = stats[bc * 2 + 1];
    float v = (s[idx] - mu) * rs;
    s[idx] = v >= 0.f ? v : 0.01f * v;
}

// ---------------- NMS stage ----------------
__global__ __launch_bounds__(256) void k_chanmax(const float* __restrict__ s,
                                                 float* __restrict__ m0) {
    int idx = blockIdx.x * blockDim.x + threadIdx.x;
    if (idx >= BHW) return;
    int b = idx >> 18, hw = idx & (HWn - 1);
    const float* p = s + ((b * Sn) << 18) + hw;
    float mx = p[0];
    #pragma unroll
    for (int c = 1; c < Sn; ++c) mx = fmaxf(mx, p[c << 18]);
    m0[idx] = mx;
}

__global__ __launch_bounds__(256) void k_rowmax(const float* __restrict__ in,
                                                float* __restrict__ out) {
    int idx = blockIdx.x * blockDim.x + threadIdx.x;
    if (idx >= BHW) return;
    int w = idx & 511;
    int base = idx - w;
    int lo = max(w - 7, 0), hi = min(w + 7, 511);
    float mx = -INFINITY;
    for (int ww = lo; ww <= hi; ++ww) mx = fmaxf(mx, in[base + ww]);
    out[idx] = mx;
}

__global__ __launch_bounds__(256) void k_colmax(const float* __restrict__ in,
                                                float* __restrict__ out) {
    int idx = blockIdx.x * blockDim.x + threadIdx.x;
    if (idx >= BHW) return;
    int w = idx & 511, h = (idx >> 9) & 511, b = idx >> 18;
    int lo = max(h - 7, 0), hi = min(h + 7, 511);
    float mx = -INFINITY;
    for (int hh = lo; hh <= hi; ++hh) mx = fmaxf(mx, in[(b << 18) + (hh << 9) + w]);
    out[idx] = mx;
}

__global__ __launch_bounds__(256) void k_expsum(const float* __restrict__ s,
                                                const float* __restrict__ m,
                                                float* __restrict__ es) {
    int idx = blockIdx.x * blockDim.x + threadIdx.x;
    if (idx >= BHW) return;
    int b = idx >> 18, hw = idx & (HWn - 1);
    const float* p = s + ((b * Sn) << 18) + hw;
    float mm = m[idx];
    float acc = 0.f;
    #pragma unroll
    for (int c = 0; c < Sn; ++c) acc += __expf(7.f * (p[c << 18] - mm));
    es[idx] = acc;
}

__global__ __launch_bounds__(256) void k_rowsum(const float* __restrict__ in,
                                                float* __restrict__ out) {
    int idx = blockIdx.x * blockDim.x + threadIdx.x;
    if (idx >= BHW) return;
    int w = idx & 511;
    int base = idx - w;
    int lo = max(w - 7, 0), hi = min(w + 7, 511);
    float acc = 0.f;
    for (int ww = lo; ww <= hi; ++ww) acc += in[base + ww];
    out[idx] = acc;
}

__global__ __launch_bounds__(256) void k_colsum(const float* __restrict__ in,
                                                float* __restrict__ out) {
    int idx = blockIdx.x * blockDim.x + threadIdx.x;
    if (idx >= BHW) return;
    int w = idx & 511, h = (idx >> 9) & 511, b = idx >> 18;
    int lo = max(h - 7, 0), hi = min(h + 7, 511);
    float acc = 0.f;
    for (int hh = lo; hh <= hi; ++hh) acc += in[(b << 18) + (hh << 9) + w];
    out[idx] = acc;
}

// ---------------- final channel softmax + outputs ----------------
__global__ __launch_bounds__(256) void k_final(const float* __restrict__ s,
        const float* __restrict__ m, const float* __restrict__ sume,
        const float* __restrict__ scl, float* __restrict__ out) {
    __shared__ float sscale[Sn];
    if (threadIdx.x < Sn) sscale[threadIdx.x] = scl[threadIdx.x];
    __syncthreads();
    int idx = blockIdx.x * blockDim.x + threadIdx.x;
    if (idx >= BHW) return;
    int b = idx >> 18, hw = idx & (HWn - 1);
    const float* p = s + ((b * Sn) << 18) + hw;
    float mm = m[idx];
    float denom = sume[idx] + 1e-8f;
    float probs[Sn];
    float mx = -INFINITY;
    #pragma unroll
    for (int c = 0; c < Sn; ++c) {
        float pr = expf(7.f * (p[c << 18] - mm)) / denom;
        probs[c] = pr;
        mx = fmaxf(mx, pr);
    }
    float e1[Sn]; float d1 = 0.f;
    #pragma unroll
    for (int c = 0; c < Sn; ++c) { e1[c] = expf(100.f * (probs[c] - mx)); d1 += e1[c]; }
    float inv = 1.f / (d1 + 1e-8f);
    float score = 0.f, scale = 0.f;
    #pragma unroll
    for (int c = 0; c < Sn; ++c) {
        float p1 = e1[c] * inv;
        score += probs[c] * p1;
        scale += sscale[c] * p1;
    }
    out[idx] = score;
    out[BHW + idx] = scale;
}

extern "C" void kernel_launch(void* const* d_in, const int* in_sizes, int n_in,
                              void* d_out, int out_size, void* d_ws, size_t ws_size,
                              hipStream_t stream) {
    const float* photos = (const float*)d_in[0];
    const float* w0     = (const float*)d_in[1];
    const float* b0     = (const float*)d_in[2];
    const float* dw1_w  = (const float*)d_in[3];
    const float* bn1a_s = (const float*)d_in[4];
    const float* bn1a_b = (const float*)d_in[5];
    const float* pw1_w  = (const float*)d_in[6];
    const float* bn1b_s = (const float*)d_in[7];
    const float* bn1b_b = (const float*)d_in[8];
    const float* dw2_w  = (const float*)d_in[9];
    const float* bn2a_s = (const float*)d_in[10];
    const float* bn2a_b = (const float*)d_in[11];
    const float* pw2_w  = (const float*)d_in[12];
    const float* bn2b_s = (const float*)d_in[13];
    const float* bn2b_b = (const float*)d_in[14];
    const float* ws_w   = (const float*)d_in[15];
    const float* bs_v   = (const float*)d_in[16];
    const float* scl    = (const float*)d_in[17];

    char* wsb = (char*)d_ws;
    float* A  = (float*)(wsb);                         // 64 MiB (B,16,H,W)
    float* Bb = (float*)(wsb + 67108864);              // 64 MiB (B,16,H,W)
    float* S  = (float*)(wsb + 134217728);             // 40 MiB (B,10,H,W)
    float* stats = Bb;                                 // 80 floats (Bb dead then)
    float* M0 = A;                                     // 4 MiB each (A dead then)
    float* M1 = A + 1 * (1 << 20);
    float* M  = A + 2 * (1 << 20);
    float* ES = A + 3 * (1 << 20);
    float* T  = A + 4 * (1 << 20);
    float* SU = A + 5 * (1 << 20);

    dim3 blk(256);
    int gNG  = NG / 256;              // 1024 blocks, 4 px/thread
    int gBHW = BHW / 256;             // 4096
    int gAll = (Bn * Sn * HWn) / 256; // 40960

    k_conv0<<<gNG, blk, 0, stream>>>(photos, w0, b0, A);
    k_ir<<<gNG, blk, 0, stream>>>(A, Bb, dw1_w, bn1a_s, bn1a_b, pw1_w, bn1b_s, bn1b_b);
    k_ir<<<gNG, blk, 0, stream>>>(Bb, A, dw2_w, bn2a_s, bn2a_b, pw2_w, bn2b_s, bn2b_b);
    k_convs<<<gNG, blk, 0, stream>>>(A, ws_w, bs_v, S);
    k_in_stats<<<Bn * Sn, blk, 0, stream>>>(S, stats);
    k_in_norm<<<gAll, blk, 0, stream>>>(S, stats);
    k_chanmax<<<gBHW, blk, 0, stream>>>(S, M0);
    k_rowmax<<<gBHW, blk, 0, stream>>>(M0, M1);
    k_colmax<<<gBHW, blk, 0, stream>>>(M1, M);
    k_expsum<<<gBHW, blk, 0, stream>>>(S, M, ES);
    k_rowsum<<<gBHW, blk, 0, stream>>>(ES, T);
    k_colsum<<<gBHW, blk, 0, stream>>>(T, SU);
    k_final<<<gBHW, blk, 0, stream>>>(S, M, SU, scl, (float*)d_out);
}

// Round 3
// 247.176 us; speedup vs baseline: 13.4206x; 2.1534x over previous
//
#include <hip/hip_runtime.h>
#include <hip/hip_bf16.h>

// Problem constants
#define Bn 4
#define Hn 512
#define Wn 512
#define Cn 16
#define Sn 10
#define HWn (Hn*Wn)          // 262144 = 1<<18
#define BHW (Bn*HWn)         // 1048576
#define NG (BHW/4)           // 262144 pixel-groups (4 pixels along W per thread)

// Load 6 consecutive row floats (w0-1 .. w0+4) with boundary zeros.
__device__ __forceinline__ void load_row6(const float* __restrict__ rp, bool valid,
                                          int w0, float* r) {
    if (valid) {
        float4 v = *reinterpret_cast<const float4*>(rp + w0);
        r[1] = v.x; r[2] = v.y; r[3] = v.z; r[4] = v.w;
        r[0] = (w0 > 0)   ? rp[w0 - 1] : 0.f;
        r[5] = (w0 < 508) ? rp[w0 + 4] : 0.f;
    } else {
        r[0] = r[1] = r[2] = r[3] = r[4] = r[5] = 0.f;
    }
}

// ---------------- conv0: 1->16, 3x3, pad 1, bias; 4 px/thread ----------------
__global__ __launch_bounds__(256) void k_conv0(const float* __restrict__ photos,
        const float* __restrict__ w0v, const float* __restrict__ b0,
        float* __restrict__ out) {
    __shared__ float wp[Cn*12];
    __shared__ float sb[Cn];
    int t = threadIdx.x;
    if (t < Cn*9) { int o = t / 9, k = t % 9; wp[o*12 + k] = w0v[t]; }
    if (t < Cn) sb[t] = b0[t];
    __syncthreads();
    int idx = blockIdx.x * 256 + t;
    int w0 = (idx & 127) << 2, h = (idx >> 7) & 511, b = idx >> 16;
    const float* pb = photos + (b << 18);
    float xr[3][6];
    #pragma unroll
    for (int dy = 0; dy < 3; ++dy) {
        int hh = h + dy - 1;
        load_row6(pb + (hh << 9), (unsigned)hh < 512u, w0, xr[dy]);
    }
    #pragma unroll
    for (int o = 0; o < Cn; ++o) {
        float4 wa = *(const float4*)&wp[o*12];
        float4 wb = *(const float4*)&wp[o*12 + 4];
        float wk8 = wp[o*12 + 8];
        float wk[9] = {wa.x, wa.y, wa.z, wa.w, wb.x, wb.y, wb.z, wb.w, wk8};
        float bv = sb[o];
        float a0 = bv, a1 = bv, a2 = bv, a3 = bv;
        #pragma unroll
        for (int dy = 0; dy < 3; ++dy)
            #pragma unroll
            for (int dx = 0; dx < 3; ++dx) {
                float wv = wk[dy*3 + dx];
                a0 += xr[dy][dx + 0] * wv;
                a1 += xr[dy][dx + 1] * wv;
                a2 += xr[dy][dx + 2] * wv;
                a3 += xr[dy][dx + 3] * wv;
            }
        float4 r; r.x = a0; r.y = a1; r.z = a2; r.w = a3;
        *reinterpret_cast<float4*>(out + ((b*Cn + o) << 18) + (h << 9) + w0) = r;
    }
}

// ---------------- inverted residual, fused dw+bn+relu6+pw+bn+skip; 4 px/thread ----
__global__ __launch_bounds__(256) void k_ir(const float* __restrict__ x,
        float* __restrict__ y, const float* __restrict__ dww,
        const float* __restrict__ as_, const float* __restrict__ ab_,
        const float* __restrict__ pww, const float* __restrict__ bs_,
        const float* __restrict__ bb_) {
    __shared__ float dwp[Cn*12];
    __shared__ float pwT[Cn*Cn];   // pwT[i*16+o] = pw[o][i]
    __shared__ float sas[Cn], sab[Cn], sbs[Cn], sbb[Cn];
    int t = threadIdx.x;
    if (t < Cn*9)  { int c = t / 9, k = t % 9; dwp[c*12 + k] = dww[t]; }
    if (t < Cn*Cn) { int o = t >> 4, i = t & 15; pwT[i*16 + o] = pww[t]; }
    if (t < Cn) { sas[t] = as_[t]; sab[t] = ab_[t]; sbs[t] = bs_[t]; sbb[t] = bb_[t]; }
    __syncthreads();
    int idx = blockIdx.x * 256 + t;
    int w0 = (idx & 127) << 2, h = (idx >> 7) & 511, b = idx >> 16;
    float acc[Cn][4];
    #pragma unroll
    for (int o = 0; o < Cn; ++o) { acc[o][0] = acc[o][1] = acc[o][2] = acc[o][3] = 0.f; }
    #pragma unroll 1
    for (int c = 0; c < Cn; ++c) {
        const float* xp = x + ((b*Cn + c) << 18);
        float xr[3][6];
        #pragma unroll
        for (int dy = 0; dy < 3; ++dy) {
            int hh = h + dy - 1;
            load_row6(xp + (hh << 9), (unsigned)hh < 512u, w0, xr[dy]);
        }
        float4 wa = *(const float4*)&dwp[c*12];
        float4 wb = *(const float4*)&dwp[c*12 + 4];
        float wk8 = dwp[c*12 + 8];
        float wk[9] = {wa.x, wa.y, wa.z, wa.w, wb.x, wb.y, wb.z, wb.w, wk8};
        float t0 = 0.f, t1 = 0.f, t2 = 0.f, t3 = 0.f;
        #pragma unroll
        for (int dy = 0; dy < 3; ++dy)
            #pragma unroll
            for (int dx = 0; dx < 3; ++dx) {
                float wv = wk[dy*3 + dx];
                t0 += xr[dy][dx + 0] * wv;
                t1 += xr[dy][dx + 1] * wv;
                t2 += xr[dy][dx + 2] * wv;
                t3 += xr[dy][dx + 3] * wv;
            }
        float sc = sas[c], sh = sab[c];
        t0 = fminf(fmaxf(t0*sc + sh, 0.f), 6.f);
        t1 = fminf(fmaxf(t1*sc + sh, 0.f), 6.f);
        t2 = fminf(fmaxf(t2*sc + sh, 0.f), 6.f);
        t3 = fminf(fmaxf(t3*sc + sh, 0.f), 6.f);
        #pragma unroll
        for (int o4 = 0; o4 < 4; ++o4) {
            float4 wq = *(const float4*)&pwT[c*16 + o4*4];
            acc[o4*4+0][0] += t0*wq.x; acc[o4*4+0][1] += t1*wq.x;
            acc[o4*4+0][2] += t2*wq.x; acc[o4*4+0][3] += t3*wq.x;
            acc[o4*4+1][0] += t0*wq.y; acc[o4*4+1][1] += t1*wq.y;
            acc[o4*4+1][2] += t2*wq.y; acc[o4*4+1][3] += t3*wq.y;
            acc[o4*4+2][0] += t0*wq.z; acc[o4*4+2][1] += t1*wq.z;
            acc[o4*4+2][2] += t2*wq.z; acc[o4*4+2][3] += t3*wq.z;
            acc[o4*4+3][0] += t0*wq.w; acc[o4*4+3][1] += t1*wq.w;
            acc[o4*4+3][2] += t2*wq.w; acc[o4*4+3][3] += t3*wq.w;
        }
    }
    #pragma unroll
    for (int o = 0; o < Cn; ++o) {
        const float* xo = x + ((b*Cn + o) << 18) + (h << 9) + w0;
        float4 xv = *(const float4*)xo;
        float sc = sbs[o], sh = sbb[o];
        float4 r;
        r.x = xv.x + acc[o][0]*sc + sh;
        r.y = xv.y + acc[o][1]*sc + sh;
        r.z = xv.z + acc[o][2]*sc + sh;
        r.w = xv.w + acc[o][3]*sc + sh;
        *reinterpret_cast<float4*>(y + ((b*Cn + o) << 18) + (h << 9) + w0) = r;
    }
}

// ---------------- score conv: 16->10, 3x3, pad 1, bias; 4 px/thread ----------------
__global__ __launch_bounds__(256) void k_convs(const float* __restrict__ x,
        const float* __restrict__ wsw, const float* __restrict__ bsv,
        float* __restrict__ s) {
    __shared__ float wp[Cn*Sn*12];   // wp[(c*10+o)*12+k]
    __shared__ float sb[Sn];
    int t = threadIdx.x;
    for (int i = t; i < Sn*Cn*9; i += 256) {
        int o = i / (Cn*9), r = i % (Cn*9), c = r / 9, k = r % 9;
        wp[(c*Sn + o)*12 + k] = wsw[i];
    }
    if (t < Sn) sb[t] = bsv[t];
    __syncthreads();
    int idx = blockIdx.x * 256 + t;
    int w0 = (idx & 127) << 2, h = (idx >> 7) & 511, b = idx >> 16;
    float acc[Sn][4];
    #pragma unroll
    for (int o = 0; o < Sn; ++o) {
        float bv = sb[o];
        acc[o][0] = bv; acc[o][1] = bv; acc[o][2] = bv; acc[o][3] = bv;
    }
    #pragma unroll 1
    for (int c = 0; c < Cn; ++c) {
        const float* xp = x + ((b*Cn + c) << 18);
        float xr[3][6];
        #pragma unroll
        for (int dy = 0; dy < 3; ++dy) {
            int hh = h + dy - 1;
            load_row6(xp + (hh << 9), (unsigned)hh < 512u, w0, xr[dy]);
        }
        #pragma unroll
        for (int o = 0; o < Sn; ++o) {
            const float* wb_ = &wp[(c*Sn + o)*12];
            float4 wa = *(const float4*)wb_;
            float4 wbv = *(const float4*)(wb_ + 4);
            float wk8 = wb_[8];
            float wk[9] = {wa.x, wa.y, wa.z, wa.w, wbv.x, wbv.y, wbv.z, wbv.w, wk8};
            #pragma unroll
            for (int dy = 0; dy < 3; ++dy)
                #pragma unroll
                for (int dx = 0; dx < 3; ++dx) {
                    float wv = wk[dy*3 + dx];
                    acc[o][0] += xr[dy][dx + 0] * wv;
                    acc[o][1] += xr[dy][dx + 1] * wv;
                    acc[o][2] += xr[dy][dx + 2] * wv;
                    acc[o][3] += xr[dy][dx + 3] * wv;
                }
        }
    }
    #pragma unroll
    for (int o = 0; o < Sn; ++o) {
        float4 r; r.x = acc[o][0]; r.y = acc[o][1]; r.z = acc[o][2]; r.w = acc[o][3];
        *reinterpret_cast<float4*>(s + ((b*Sn + o) << 18) + (h << 9) + w0) = r;
    }
}

// ---------------- instance norm stage 1: partial sums (32 chunks/plane) ----------
__global__ __launch_bounds__(256) void k_in_part(const float* __restrict__ s,
                                                 double* __restrict__ part) {
    // blockIdx.x in [0, 40*32): bc = blk/32, chunk = blk%32 (8192 floats each)
    int bc = blockIdx.x >> 5, ch = blockIdx.x & 31;
    const float4* p4 = (const float4*)(s + ((size_t)bc << 18) + (ch << 13));
    int t = threadIdx.x;
    double sum = 0.0, sq = 0.0;
    #pragma unroll
    for (int i = 0; i < 8; ++i) {
        float4 v = p4[t + i * 256];
        sum += (double)v.x + (double)v.y + (double)v.z + (double)v.w;
        sq  += (double)v.x*v.x + (double)v.y*v.y + (double)v.z*v.z + (double)v.w*v.w;
    }
    __shared__ double ssum[256], ssq[256];
    ssum[t] = sum; ssq[t] = sq;
    __syncthreads();
    for (int off = 128; off > 0; off >>= 1) {
        if (t < off) { ssum[t] += ssum[t + off]; ssq[t] += ssq[t + off]; }
        __syncthreads();
    }
    if (t == 0) {
        part[blockIdx.x * 2]     = ssum[0];
        part[blockIdx.x * 2 + 1] = ssq[0];
    }
}

// ---------------- instance norm stage 2: finalize {mu, rsqrt} ----------------
__global__ __launch_bounds__(64) void k_in_fin(const double* __restrict__ part,
                                               float2* __restrict__ stats) {
    int bc = blockIdx.x;
    int t = threadIdx.x;
    double sum = 0.0, sq = 0.0;
    if (t < 32) { sum = part[(bc * 32 + t) * 2]; sq = part[(bc * 32 + t) * 2 + 1]; }
    #pragma unroll
    for (int off = 32; off > 0; off >>= 1) {
        sum += __shfl_xor(sum, off);
        sq  += __shfl_xor(sq, off);
    }
    if (t == 0) {
        double mu = sum / (double)HWn;
        double var = sq / (double)HWn - mu * mu;
        float2 st; st.x = (float)mu; st.y = rsqrtf((float)var + 1e-5f);
        stats[bc] = st;
    }
}

// ------- fused: in-place instance-norm + leaky-relu + channel-max; 4 px/thread ----
__global__ __launch_bounds__(256) void k_norm_chanmax(float* __restrict__ s,
        const float2* __restrict__ stats, float* __restrict__ m0) {
    int idx = blockIdx.x * 256 + threadIdx.x;       // 0..NG-1
    int pb = idx << 2;
    int b = pb >> 18, hw = pb & (HWn - 1);
    float* p = s + ((size_t)(b * Sn) << 18) + hw;
    float4 mx = make_float4(-INFINITY, -INFINITY, -INFINITY, -INFINITY);
    #pragma unroll
    for (int c = 0; c < Sn; ++c) {
        float2 st = stats[b * Sn + c];
        float4 v = *reinterpret_cast<const float4*>(p + ((size_t)c << 18));
        v.x = (v.x - st.x) * st.y; v.x = v.x >= 0.f ? v.x : 0.01f * v.x;
        v.y = (v.y - st.x) * st.y; v.y = v.y >= 0.f ? v.y : 0.01f * v.y;
        v.z = (v.z - st.x) * st.y; v.z = v.z >= 0.f ? v.z : 0.01f * v.z;
        v.w = (v.w - st.x) * st.y; v.w = v.w >= 0.f ? v.w : 0.01f * v.w;
        *reinterpret_cast<float4*>(p + ((size_t)c << 18)) = v;
        mx.x = fmaxf(mx.x, v.x); mx.y = fmaxf(mx.y, v.y);
        mx.z = fmaxf(mx.z, v.z); mx.w = fmaxf(mx.w, v.w);
    }
    *reinterpret_cast<float4*>(m0 + pb) = mx;
}

// ---------------- NMS separable max passes ----------------
__global__ __launch_bounds__(256) void k_rowmax(const float* __restrict__ in,
                                                float* __restrict__ out) {
    int idx = blockIdx.x * blockDim.x + threadIdx.x;
    if (idx >= BHW) return;
    int w = idx & 511;
    int base = idx - w;
    int lo = max(w - 7, 0), hi = min(w + 7, 511);
    float mx = -INFINITY;
    for (int ww = lo; ww <= hi; ++ww) mx = fmaxf(mx, in[base + ww]);
    out[idx] = mx;
}

__global__ __launch_bounds__(256) void k_colmax(const float* __restrict__ in,
                                                float* __restrict__ out) {
    int idx = blockIdx.x * blockDim.x + threadIdx.x;
    if (idx >= BHW) return;
    int w = idx & 511, h = (idx >> 9) & 511, b = idx >> 18;
    int lo = max(h - 7, 0), hi = min(h + 7, 511);
    float mx = -INFINITY;
    for (int hh = lo; hh <= hi; ++hh) mx = fmaxf(mx, in[(b << 18) + (hh << 9) + w]);
    out[idx] = mx;
}

// ---------------- exp-sum over channels; 4 px/thread ----------------
__global__ __launch_bounds__(256) void k_expsum(const float* __restrict__ s,
                                                const float* __restrict__ m,
                                                float* __restrict__ es) {
    int idx = blockIdx.x * 256 + threadIdx.x;
    int pb = idx << 2;
    int b = pb >> 18, hw = pb & (HWn - 1);
    const float* p = s + ((size_t)(b * Sn) << 18) + hw;
    float4 mm = *reinterpret_cast<const float4*>(m + pb);
    float4 acc = make_float4(0.f, 0.f, 0.f, 0.f);
    #pragma unroll
    for (int c = 0; c < Sn; ++c) {
        float4 v = *reinterpret_cast<const float4*>(p + ((size_t)c << 18));
        acc.x += __expf(7.f * (v.x - mm.x));
        acc.y += __expf(7.f * (v.y - mm.y));
        acc.z += __expf(7.f * (v.z - mm.z));
        acc.w += __expf(7.f * (v.w - mm.w));
    }
    *reinterpret_cast<float4*>(es + pb) = acc;
}

// ---------------- NMS separable sum passes ----------------
__global__ __launch_bounds__(256) void k_rowsum(const float* __restrict__ in,
                                                float* __restrict__ out) {
    int idx = blockIdx.x * blockDim.x + threadIdx.x;
    if (idx >= BHW) return;
    int w = idx & 511;
    int base = idx - w;
    int lo = max(w - 7, 0), hi = min(w + 7, 511);
    float acc = 0.f;
    for (int ww = lo; ww <= hi; ++ww) acc += in[base + ww];
    out[idx] = acc;
}

__global__ __launch_bounds__(256) void k_colsum(const float* __restrict__ in,
                                                float* __restrict__ out) {
    int idx = blockIdx.x * blockDim.x + threadIdx.x;
    if (idx >= BHW) return;
    int w = idx & 511, h = (idx >> 9) & 511, b = idx >> 18;
    int lo = max(h - 7, 0), hi = min(h + 7, 511);
    float acc = 0.f;
    for (int hh = lo; hh <= hi; ++hh) acc += in[(b << 18) + (hh << 9) + w];
    out[idx] = acc;
}

// ---------------- final channel softmax + outputs ----------------
__global__ __launch_bounds__(256) void k_final(const float* __restrict__ s,
        const float* __restrict__ m, const float* __restrict__ sume,
        const float* __restrict__ scl, float* __restrict__ out) {
    __shared__ float sscale[Sn];
    if (threadIdx.x < Sn) sscale[threadIdx.x] = scl[threadIdx.x];
    __syncthreads();
    int idx = blockIdx.x * blockDim.x + threadIdx.x;
    if (idx >= BHW) return;
    int b = idx >> 18, hw = idx & (HWn - 1);
    const float* p = s + ((b * Sn) << 18) + hw;
    float mm = m[idx];
    float denom = sume[idx] + 1e-8f;
    float probs[Sn];
    float mx = -INFINITY;
    #pragma unroll
    for (int c = 0; c < Sn; ++c) {
        float pr = expf(7.f * (p[c << 18] - mm)) / denom;
        probs[c] = pr;
        mx = fmaxf(mx, pr);
    }
    float e1[Sn]; float d1 = 0.f;
    #pragma unroll
    for (int c = 0; c < Sn; ++c) { e1[c] = expf(100.f * (probs[c] - mx)); d1 += e1[c]; }
    float inv = 1.f / (d1 + 1e-8f);
    float score = 0.f, scale = 0.f;
    #pragma unroll
    for (int c = 0; c < Sn; ++c) {
        float p1 = e1[c] * inv;
        score += probs[c] * p1;
        scale += sscale[c] * p1;
    }
    out[idx] = score;
    out[BHW + idx] = scale;
}

extern "C" void kernel_launch(void* const* d_in, const int* in_sizes, int n_in,
                              void* d_out, int out_size, void* d_ws, size_t ws_size,
                              hipStream_t stream) {
    const float* photos = (const float*)d_in[0];
    const float* w0     = (const float*)d_in[1];
    const float* b0     = (const float*)d_in[2];
    const float* dw1_w  = (const float*)d_in[3];
    const float* bn1a_s = (const float*)d_in[4];
    const float* bn1a_b = (const float*)d_in[5];
    const float* pw1_w  = (const float*)d_in[6];
    const float* bn1b_s = (const float*)d_in[7];
    const float* bn1b_b = (const float*)d_in[8];
    const float* dw2_w  = (const float*)d_in[9];
    const float* bn2a_s = (const float*)d_in[10];
    const float* bn2a_b = (const float*)d_in[11];
    const float* pw2_w  = (const float*)d_in[12];
    const float* bn2b_s = (const float*)d_in[13];
    const float* bn2b_b = (const float*)d_in[14];
    const float* ws_w   = (const float*)d_in[15];
    const float* bs_v   = (const float*)d_in[16];
    const float* scl    = (const float*)d_in[17];

    char* wsb = (char*)d_ws;
    float* A  = (float*)(wsb);                         // 64 MiB (B,16,H,W)
    float* Bb = (float*)(wsb + 67108864);              // 64 MiB (B,16,H,W)
    float* S  = (float*)(wsb + 134217728);             // 40 MiB (B,10,H,W)
    // After k_convs, A and Bb are dead -> reuse for small temporaries.
    float2* stats = (float2*)Bb;                       // 40 float2
    double* part  = (double*)(Bb + 1024);              // 1280*2 doubles (20 KB)
    float* M0 = A;                                     // 4 MiB each
    float* M1 = A + 1 * (1 << 20);
    float* M  = A + 2 * (1 << 20);
    float* ES = A + 3 * (1 << 20);
    float* T  = A + 4 * (1 << 20);
    float* SU = A + 5 * (1 << 20);

    dim3 blk(256);
    int gNG  = NG / 256;              // 1024 blocks, 4 px/thread
    int gBHW = BHW / 256;             // 4096

    k_conv0<<<gNG, blk, 0, stream>>>(photos, w0, b0, A);
    k_ir<<<gNG, blk, 0, stream>>>(A, Bb, dw1_w, bn1a_s, bn1a_b, pw1_w, bn1b_s, bn1b_b);
    k_ir<<<gNG, blk, 0, stream>>>(Bb, A, dw2_w, bn2a_s, bn2a_b, pw2_w, bn2b_s, bn2b_b);
    k_convs<<<gNG, blk, 0, stream>>>(A, ws_w, bs_v, S);
    k_in_part<<<Bn * Sn * 32, blk, 0, stream>>>(S, part);
    k_in_fin<<<Bn * Sn, dim3(64), 0, stream>>>(part, stats);
    k_norm_chanmax<<<gNG, blk, 0, stream>>>(S, stats, M0);
    k_rowmax<<<gBHW, blk, 0, stream>>>(M0, M1);
    k_colmax<<<gBHW, blk, 0, stream>>>(M1, M);
    k_expsum<<<gNG, blk, 0, stream>>>(S, M, ES);
    k_rowsum<<<gBHW, blk, 0, stream>>>(ES, T);
    k_colsum<<<gBHW, blk, 0, stream>>>(T, SU);
    k_final<<<gBHW, blk, 0, stream>>>(S, M, SU, scl, (float*)d_out);
}

// Round 4
// 232.108 us; speedup vs baseline: 14.2918x; 1.0649x over previous
//
#include <hip/hip_runtime.h>
#include <hip/hip_bf16.h>

// Problem constants
#define Bn 4
#define Hn 512
#define Wn 512
#define Cn 16
#define Sn 10
#define HWn (Hn*Wn)          // 262144 = 1<<18
#define BHW (Bn*HWn)         // 1048576
#define NG (BHW/4)           // 262144 pixel-groups (4 pixels along W per thread)

// Load 6 consecutive row floats (w0-1 .. w0+4) with boundary zeros.
__device__ __forceinline__ void load_row6(const float* __restrict__ rp, bool valid,
                                          int w0, float* r) {
    if (valid) {
        float4 v = *reinterpret_cast<const float4*>(rp + w0);
        r[1] = v.x; r[2] = v.y; r[3] = v.z; r[4] = v.w;
        r[0] = (w0 > 0)   ? rp[w0 - 1] : 0.f;
        r[5] = (w0 < 508) ? rp[w0 + 4] : 0.f;
    } else {
        r[0] = r[1] = r[2] = r[3] = r[4] = r[5] = 0.f;
    }
}

// ---------------- conv0: 1->16, 3x3, pad 1, bias; 4 px/thread ----------------
__global__ __launch_bounds__(256) void k_conv0(const float* __restrict__ photos,
        const float* __restrict__ w0v, const float* __restrict__ b0,
        float* __restrict__ out) {
    __shared__ float wp[Cn*12];
    __shared__ float sb[Cn];
    int t = threadIdx.x;
    if (t < Cn*9) { int o = t / 9, k = t % 9; wp[o*12 + k] = w0v[t]; }
    if (t < Cn) sb[t] = b0[t];
    __syncthreads();
    int idx = blockIdx.x * 256 + t;
    int w0 = (idx & 127) << 2, h = (idx >> 7) & 511, b = idx >> 16;
    const float* pb = photos + (b << 18);
    float xr[3][6];
    #pragma unroll
    for (int dy = 0; dy < 3; ++dy) {
        int hh = h + dy - 1;
        load_row6(pb + (hh << 9), (unsigned)hh < 512u, w0, xr[dy]);
    }
    #pragma unroll
    for (int o = 0; o < Cn; ++o) {
        float4 wa = *(const float4*)&wp[o*12];
        float4 wb = *(const float4*)&wp[o*12 + 4];
        float wk8 = wp[o*12 + 8];
        float wk[9] = {wa.x, wa.y, wa.z, wa.w, wb.x, wb.y, wb.z, wb.w, wk8};
        float bv = sb[o];
        float a0 = bv, a1 = bv, a2 = bv, a3 = bv;
        #pragma unroll
        for (int dy = 0; dy < 3; ++dy)
            #pragma unroll
            for (int dx = 0; dx < 3; ++dx) {
                float wv = wk[dy*3 + dx];
                a0 += xr[dy][dx + 0] * wv;
                a1 += xr[dy][dx + 1] * wv;
                a2 += xr[dy][dx + 2] * wv;
                a3 += xr[dy][dx + 3] * wv;
            }
        float4 r; r.x = a0; r.y = a1; r.z = a2; r.w = a3;
        *reinterpret_cast<float4*>(out + ((b*Cn + o) << 18) + (h << 9) + w0) = r;
    }
}

// Depthwise+bn+relu6+pw accumulate for one channel (macro: guarantees LDS access
// stays ds_*, all acc indices compile-time).
#define IR_COMPUTE(cc, xr) do {                                                 \
    const int c_ = (cc);                                                        \
    float4 wa_ = *(const float4*)&dwp[c_*12];                                   \
    float4 wb_ = *(const float4*)&dwp[c_*12 + 4];                               \
    float wk8_ = dwp[c_*12 + 8];                                                \
    float wk_[9] = {wa_.x, wa_.y, wa_.z, wa_.w, wb_.x, wb_.y, wb_.z, wb_.w, wk8_}; \
    float t0 = 0.f, t1 = 0.f, t2 = 0.f, t3 = 0.f;                               \
    _Pragma("unroll")                                                           \
    for (int dy = 0; dy < 3; ++dy) {                                            \
        _Pragma("unroll")                                                       \
        for (int dx = 0; dx < 3; ++dx) {                                        \
            float wv = wk_[dy*3 + dx];                                          \
            t0 += xr[dy][dx + 0] * wv;                                          \
            t1 += xr[dy][dx + 1] * wv;                                          \
            t2 += xr[dy][dx + 2] * wv;                                          \
            t3 += xr[dy][dx + 3] * wv;                                          \
        }                                                                       \
    }                                                                           \
    float sc_ = sas[c_], sh_ = sab[c_];                                         \
    t0 = fminf(fmaxf(t0*sc_ + sh_, 0.f), 6.f);                                  \
    t1 = fminf(fmaxf(t1*sc_ + sh_, 0.f), 6.f);                                  \
    t2 = fminf(fmaxf(t2*sc_ + sh_, 0.f), 6.f);                                  \
    t3 = fminf(fmaxf(t3*sc_ + sh_, 0.f), 6.f);                                  \
    _Pragma("unroll")                                                           \
    for (int o4 = 0; o4 < 4; ++o4) {                                            \
        float4 wq = *(const float4*)&pwT[c_*16 + o4*4];                         \
        acc[o4*4+0][0] += t0*wq.x; acc[o4*4+0][1] += t1*wq.x;                   \
        acc[o4*4+0][2] += t2*wq.x; acc[o4*4+0][3] += t3*wq.x;                   \
        acc[o4*4+1][0] += t0*wq.y; acc[o4*4+1][1] += t1*wq.y;                   \
        acc[o4*4+1][2] += t2*wq.y; acc[o4*4+1][3] += t3*wq.y;                   \
        acc[o4*4+2][0] += t0*wq.z; acc[o4*4+2][1] += t1*wq.z;                   \
        acc[o4*4+2][2] += t2*wq.z; acc[o4*4+2][3] += t3*wq.z;                   \
        acc[o4*4+3][0] += t0*wq.w; acc[o4*4+3][1] += t1*wq.w;                   \
        acc[o4*4+3][2] += t2*wq.w; acc[o4*4+3][3] += t3*wq.w;                   \
    }                                                                           \
} while (0)

// ------ inverted residual, software-pipelined over channels; 4 px/thread ------
__global__ __launch_bounds__(256) void k_ir(const float* __restrict__ x,
        float* __restrict__ y, const float* __restrict__ dww,
        const float* __restrict__ as_, const float* __restrict__ ab_,
        const float* __restrict__ pww, const float* __restrict__ bs_,
        const float* __restrict__ bb_) {
    __shared__ float dwp[Cn*12];
    __shared__ float pwT[Cn*Cn];   // pwT[i*16+o] = pw[o][i]
    __shared__ float sas[Cn], sab[Cn], sbs[Cn], sbb[Cn];
    int t = threadIdx.x;
    if (t < Cn*9)  { int c = t / 9, k = t % 9; dwp[c*12 + k] = dww[t]; }
    if (t < Cn*Cn) { int o = t >> 4, i = t & 15; pwT[i*16 + o] = pww[t]; }
    if (t < Cn) { sas[t] = as_[t]; sab[t] = ab_[t]; sbs[t] = bs_[t]; sbb[t] = bb_[t]; }
    __syncthreads();
    int idx = blockIdx.x * 256 + t;
    int w0 = (idx & 127) << 2, h = (idx >> 7) & 511, b = idx >> 16;
    const float* xb = x + ((size_t)b << 22);   // b*16 planes
    float acc[Cn][4];
    #pragma unroll
    for (int o = 0; o < Cn; ++o) { acc[o][0] = acc[o][1] = acc[o][2] = acc[o][3] = 0.f; }
    float xrA[3][6], xrB[3][6];
    #pragma unroll
    for (int dy = 0; dy < 3; ++dy) {
        int hh = h + dy - 1;
        load_row6(xb + (hh << 9), (unsigned)hh < 512u, w0, xrA[dy]);
    }
    #pragma unroll 1
    for (int c = 0; c < Cn; c += 2) {
        #pragma unroll
        for (int dy = 0; dy < 3; ++dy) {
            int hh = h + dy - 1;
            load_row6(xb + ((c + 1) << 18) + (hh << 9), (unsigned)hh < 512u, w0, xrB[dy]);
        }
        IR_COMPUTE(c, xrA);
        if (c + 2 < Cn) {
            #pragma unroll
            for (int dy = 0; dy < 3; ++dy) {
                int hh = h + dy - 1;
                load_row6(xb + ((c + 2) << 18) + (hh << 9), (unsigned)hh < 512u, w0, xrA[dy]);
            }
        }
        IR_COMPUTE(c + 1, xrB);
    }
    #pragma unroll
    for (int o = 0; o < Cn; ++o) {
        const float* xo = xb + (o << 18) + (h << 9) + w0;
        float4 xv = *(const float4*)xo;
        float sc = sbs[o], sh = sbb[o];
        float4 r;
        r.x = xv.x + acc[o][0]*sc + sh;
        r.y = xv.y + acc[o][1]*sc + sh;
        r.z = xv.z + acc[o][2]*sc + sh;
        r.w = xv.w + acc[o][3]*sc + sh;
        *reinterpret_cast<float4*>(y + ((size_t)b << 22) + (o << 18) + (h << 9) + w0) = r;
    }
}

#define CONVS_COMPUTE(cc, xr) do {                                              \
    const int c_ = (cc);                                                        \
    _Pragma("unroll")                                                           \
    for (int o = 0; o < Sn; ++o) {                                              \
        const float* wb_ = &wp[(c_*Sn + o)*12];                                 \
        float4 wa_ = *(const float4*)wb_;                                       \
        float4 wv_ = *(const float4*)(wb_ + 4);                                 \
        float wk8_ = wb_[8];                                                    \
        float wk_[9] = {wa_.x, wa_.y, wa_.z, wa_.w, wv_.x, wv_.y, wv_.z, wv_.w, wk8_}; \
        _Pragma("unroll")                                                       \
        for (int dy = 0; dy < 3; ++dy) {                                        \
            _Pragma("unroll")                                                   \
            for (int dx = 0; dx < 3; ++dx) {                                    \
                float wv = wk_[dy*3 + dx];                                      \
                acc[o][0] += xr[dy][dx + 0] * wv;                               \
                acc[o][1] += xr[dy][dx + 1] * wv;                               \
                acc[o][2] += xr[dy][dx + 2] * wv;                               \
                acc[o][3] += xr[dy][dx + 3] * wv;                               \
            }                                                                   \
        }                                                                       \
    }                                                                           \
} while (0)

// ------ score conv 16->10, software-pipelined over channels; 4 px/thread ------
__global__ __launch_bounds__(256) void k_convs(const float* __restrict__ x,
        const float* __restrict__ wsw, const float* __restrict__ bsv,
        float* __restrict__ s) {
    __shared__ float wp[Cn*Sn*12];   // wp[(c*10+o)*12+k]
    __shared__ float sb[Sn];
    int t = threadIdx.x;
    for (int i = t; i < Sn*Cn*9; i += 256) {
        int o = i / (Cn*9), r = i % (Cn*9), c = r / 9, k = r % 9;
        wp[(c*Sn + o)*12 + k] = wsw[i];
    }
    if (t < Sn) sb[t] = bsv[t];
    __syncthreads();
    int idx = blockIdx.x * 256 + t;
    int w0 = (idx & 127) << 2, h = (idx >> 7) & 511, b = idx >> 16;
    const float* xb = x + ((size_t)b << 22);
    float acc[Sn][4];
    #pragma unroll
    for (int o = 0; o < Sn; ++o) {
        float bv = sb[o];
        acc[o][0] = bv; acc[o][1] = bv; acc[o][2] = bv; acc[o][3] = bv;
    }
    float xrA[3][6], xrB[3][6];
    #pragma unroll
    for (int dy = 0; dy < 3; ++dy) {
        int hh = h + dy - 1;
        load_row6(xb + (hh << 9), (unsigned)hh < 512u, w0, xrA[dy]);
    }
    #pragma unroll 1
    for (int c = 0; c < Cn; c += 2) {
        #pragma unroll
        for (int dy = 0; dy < 3; ++dy) {
            int hh = h + dy - 1;
            load_row6(xb + ((c + 1) << 18) + (hh << 9), (unsigned)hh < 512u, w0, xrB[dy]);
        }
        CONVS_COMPUTE(c, xrA);
        if (c + 2 < Cn) {
            #pragma unroll
            for (int dy = 0; dy < 3; ++dy) {
                int hh = h + dy - 1;
                load_row6(xb + ((c + 2) << 18) + (hh << 9), (unsigned)hh < 512u, w0, xrA[dy]);
            }
        }
        CONVS_COMPUTE(c + 1, xrB);
    }
    #pragma unroll
    for (int o = 0; o < Sn; ++o) {
        float4 r; r.x = acc[o][0]; r.y = acc[o][1]; r.z = acc[o][2]; r.w = acc[o][3];
        *reinterpret_cast<float4*>(s + ((b*Sn + o) << 18) + (h << 9) + w0) = r;
    }
}

// ---------------- instance norm stage 1: partial sums (32 chunks/plane) ----------
__global__ __launch_bounds__(256) void k_in_part(const float* __restrict__ s,
                                                 double* __restrict__ part) {
    int bc = blockIdx.x >> 5, ch = blockIdx.x & 31;
    const float4* p4 = (const float4*)(s + ((size_t)bc << 18) + (ch << 13));
    int t = threadIdx.x;
    double sum = 0.0, sq = 0.0;
    #pragma unroll
    for (int i = 0; i < 8; ++i) {
        float4 v = p4[t + i * 256];
        sum += (double)v.x + (double)v.y + (double)v.z + (double)v.w;
        sq  += (double)v.x*v.x + (double)v.y*v.y + (double)v.z*v.z + (double)v.w*v.w;
    }
    __shared__ double ssum[256], ssq[256];
    ssum[t] = sum; ssq[t] = sq;
    __syncthreads();
    for (int off = 128; off > 0; off >>= 1) {
        if (t < off) { ssum[t] += ssum[t + off]; ssq[t] += ssq[t + off]; }
        __syncthreads();
    }
    if (t == 0) {
        part[blockIdx.x * 2]     = ssum[0];
        part[blockIdx.x * 2 + 1] = ssq[0];
    }
}

// ---------------- instance norm stage 2: finalize {mu, rsqrt} ----------------
__global__ __launch_bounds__(64) void k_in_fin(const double* __restrict__ part,
                                               float2* __restrict__ stats) {
    int bc = blockIdx.x;
    int t = threadIdx.x;
    double sum = 0.0, sq = 0.0;
    if (t < 32) { sum = part[(bc * 32 + t) * 2]; sq = part[(bc * 32 + t) * 2 + 1]; }
    #pragma unroll
    for (int off = 32; off > 0; off >>= 1) {
        sum += __shfl_xor(sum, off);
        sq  += __shfl_xor(sq, off);
    }
    if (t == 0) {
        double mu = sum / (double)HWn;
        double var = sq / (double)HWn - mu * mu;
        float2 st; st.x = (float)mu; st.y = rsqrtf((float)var + 1e-5f);
        stats[bc] = st;
    }
}

// norm + leaky-relu applied on the fly (S stays raw everywhere)
__device__ __forceinline__ float nrm(float v, float2 st) {
    float r = (v - st.x) * st.y;
    return r >= 0.f ? r : 0.01f * r;
}

// ---- R1: chanmax + rowmax. One block per (b,h) row; 2 px/thread. ----
__global__ __launch_bounds__(256) void k_chan_rowmax(const float* __restrict__ s,
        const float2* __restrict__ stats, float* __restrict__ m1) {
    __shared__ float rowbuf[512];
    int bh = blockIdx.x;
    int b = bh >> 9, h = bh & 511;
    int t = threadIdx.x, w0 = t << 1;
    const float* sp = s + ((size_t)(b * Sn) << 18) + (h << 9) + w0;
    float mx0 = -INFINITY, mx1 = -INFINITY;
    #pragma unroll
    for (int c = 0; c < Sn; ++c) {
        float2 st = stats[b * Sn + c];
        float2 v = *reinterpret_cast<const float2*>(sp + ((size_t)c << 18));
        mx0 = fmaxf(mx0, nrm(v.x, st));
        mx1 = fmaxf(mx1, nrm(v.y, st));
    }
    rowbuf[w0] = mx0; rowbuf[w0 + 1] = mx1;
    __syncthreads();
    float2 o;
    {
        int lo = max(w0 - 7, 0), hi = min(w0 + 7, 511);
        float m = -INFINITY;
        for (int ww = lo; ww <= hi; ++ww) m = fmaxf(m, rowbuf[ww]);
        o.x = m;
        int w1 = w0 + 1;
        lo = max(w1 - 7, 0); hi = min(w1 + 7, 511);
        m = -INFINITY;
        for (int ww = lo; ww <= hi; ++ww) m = fmaxf(m, rowbuf[ww]);
        o.y = m;
    }
    *reinterpret_cast<float2*>(m1 + (bh << 9) + w0) = o;
}

// ---- R2: colmax -> M, expsum, rowsum -> T. One block per (b,h) row. ----
__global__ __launch_bounds__(256) void k_col_expsum(const float* __restrict__ s,
        const float2* __restrict__ stats, const float* __restrict__ m1,
        float* __restrict__ mfull, float* __restrict__ tout) {
    __shared__ float esbuf[512];
    int bh = blockIdx.x;
    int b = bh >> 9, h = bh & 511;
    int t = threadIdx.x, w0 = t << 1;
    // colmax over M1 rows h-7..h+7
    int lo = max(h - 7, 0), hi = min(h + 7, 511);
    float2 m = make_float2(-INFINITY, -INFINITY);
    for (int hh = lo; hh <= hi; ++hh) {
        float2 v = *reinterpret_cast<const float2*>(m1 + ((size_t)b << 18) + (hh << 9) + w0);
        m.x = fmaxf(m.x, v.x); m.y = fmaxf(m.y, v.y);
    }
    *reinterpret_cast<float2*>(mfull + (bh << 9) + w0) = m;
    // channel exp-sum at this pixel
    const float* sp = s + ((size_t)(b * Sn) << 18) + (h << 9) + w0;
    float es0 = 0.f, es1 = 0.f;
    #pragma unroll
    for (int c = 0; c < Sn; ++c) {
        float2 st = stats[b * Sn + c];
        float2 v = *reinterpret_cast<const float2*>(sp + ((size_t)c << 18));
        es0 += __expf(7.f * (nrm(v.x, st) - m.x));
        es1 += __expf(7.f * (nrm(v.y, st) - m.y));
    }
    esbuf[w0] = es0; esbuf[w0 + 1] = es1;
    __syncthreads();
    float2 o;
    {
        int wlo = max(w0 - 7, 0), whi = min(w0 + 7, 511);
        float a = 0.f;
        for (int ww = wlo; ww <= whi; ++ww) a += esbuf[ww];
        o.x = a;
        int w1 = w0 + 1;
        wlo = max(w1 - 7, 0); whi = min(w1 + 7, 511);
        a = 0.f;
        for (int ww = wlo; ww <= whi; ++ww) a += esbuf[ww];
        o.y = a;
    }
    *reinterpret_cast<float2*>(tout + (bh << 9) + w0) = o;
}

// ---- R3: colsum -> SU, channel softmax, outputs. One block per (b,h) row. ----
__global__ __launch_bounds__(256) void k_final(const float* __restrict__ s,
        const float2* __restrict__ stats, const float* __restrict__ mfull,
        const float* __restrict__ tin, const float* __restrict__ scl,
        float* __restrict__ out) {
    __shared__ float sscale[Sn];
    int t = threadIdx.x;
    if (t < Sn) sscale[t] = scl[t];
    __syncthreads();
    int bh = blockIdx.x;
    int b = bh >> 9, h = bh & 511;
    int w0 = t << 1;
    int lo = max(h - 7, 0), hi = min(h + 7, 511);
    float2 su = make_float2(0.f, 0.f);
    for (int hh = lo; hh <= hi; ++hh) {
        float2 v = *reinterpret_cast<const float2*>(tin + ((size_t)b << 18) + (hh << 9) + w0);
        su.x += v.x; su.y += v.y;
    }
    float2 m = *reinterpret_cast<const float2*>(mfull + (bh << 9) + w0);
    float d0 = 1.f / (su.x + 1e-8f), d1i = 1.f / (su.y + 1e-8f);
    const float* sp = s + ((size_t)(b * Sn) << 18) + (h << 9) + w0;
    float pr0[Sn], pr1[Sn];
    float mx0 = -INFINITY, mx1 = -INFINITY;
    #pragma unroll
    for (int c = 0; c < Sn; ++c) {
        float2 st = stats[b * Sn + c];
        float2 v = *reinterpret_cast<const float2*>(sp + ((size_t)c << 18));
        float p0 = expf(7.f * (nrm(v.x, st) - m.x)) * d0;
        float p1 = expf(7.f * (nrm(v.y, st) - m.y)) * d1i;
        pr0[c] = p0; pr1[c] = p1;
        mx0 = fmaxf(mx0, p0); mx1 = fmaxf(mx1, p1);
    }
    float e0[Sn], e1[Sn];
    float s0 = 0.f, s1 = 0.f;
    #pragma unroll
    for (int c = 0; c < Sn; ++c) {
        e0[c] = expf(100.f * (pr0[c] - mx0)); s0 += e0[c];
        e1[c] = expf(100.f * (pr1[c] - mx1)); s1 += e1[c];
    }
    float i0 = 1.f / (s0 + 1e-8f), i1 = 1.f / (s1 + 1e-8f);
    float sc0 = 0.f, sc1 = 0.f, sl0 = 0.f, sl1 = 0.f;
    #pragma unroll
    for (int c = 0; c < Sn; ++c) {
        float p0 = e0[c] * i0, p1 = e1[c] * i1;
        sc0 += pr0[c] * p0; sl0 += sscale[c] * p0;
        sc1 += pr1[c] * p1; sl1 += sscale[c] * p1;
    }
    int oi = (bh << 9) + w0;
    float2 r0; r0.x = sc0; r0.y = sc1;
    float2 r1; r1.x = sl0; r1.y = sl1;
    *reinterpret_cast<float2*>(out + oi) = r0;
    *reinterpret_cast<float2*>(out + BHW + oi) = r1;
}

extern "C" void kernel_launch(void* const* d_in, const int* in_sizes, int n_in,
                              void* d_out, int out_size, void* d_ws, size_t ws_size,
                              hipStream_t stream) {
    const float* photos = (const float*)d_in[0];
    const float* w0     = (const float*)d_in[1];
    const float* b0     = (const float*)d_in[2];
    const float* dw1_w  = (const float*)d_in[3];
    const float* bn1a_s = (const float*)d_in[4];
    const float* bn1a_b = (const float*)d_in[5];
    const float* pw1_w  = (const float*)d_in[6];
    const float* bn1b_s = (const float*)d_in[7];
    const float* bn1b_b = (const float*)d_in[8];
    const float* dw2_w  = (const float*)d_in[9];
    const float* bn2a_s = (const float*)d_in[10];
    const float* bn2a_b = (const float*)d_in[11];
    const float* pw2_w  = (const float*)d_in[12];
    const float* bn2b_s = (const float*)d_in[13];
    const float* bn2b_b = (const float*)d_in[14];
    const float* ws_w   = (const float*)d_in[15];
    const float* bs_v   = (const float*)d_in[16];
    const float* scl    = (const float*)d_in[17];

    char* wsb = (char*)d_ws;
    float* A  = (float*)(wsb);                         // 64 MiB (B,16,H,W)
    float* Bb = (float*)(wsb + 67108864);              // 64 MiB (B,16,H,W)
    float* S  = (float*)(wsb + 134217728);             // 40 MiB raw conv output
    // After k_convs, A and Bb are dead -> reuse.
    float2* stats = (float2*)Bb;                       // 40 float2
    double* part  = (double*)(Bb + 1024);              // 1280*2 doubles
    float* M1 = A;                                     // 4 MiB each
    float* M  = A + 1 * (1 << 20);
    float* T  = A + 2 * (1 << 20);

    dim3 blk(256);
    int gNG  = NG / 256;              // 1024 blocks, 4 px/thread
    int gROW = Bn * Hn;               // 2048 row-blocks, 2 px/thread

    k_conv0<<<gNG, blk, 0, stream>>>(photos, w0, b0, A);
    k_ir<<<gNG, blk, 0, stream>>>(A, Bb, dw1_w, bn1a_s, bn1a_b, pw1_w, bn1b_s, bn1b_b);
    k_ir<<<gNG, blk, 0, stream>>>(Bb, A, dw2_w, bn2a_s, bn2a_b, pw2_w, bn2b_s, bn2b_b);
    k_convs<<<gNG, blk, 0, stream>>>(A, ws_w, bs_v, S);
    k_in_part<<<Bn * Sn * 32, blk, 0, stream>>>(S, part);
    k_in_fin<<<Bn * Sn, dim3(64), 0, stream>>>(part, stats);
    k_chan_rowmax<<<gROW, blk, 0, stream>>>(S, stats, M1);
    k_col_expsum<<<gROW, blk, 0, stream>>>(S, stats, M1, M, T);
    k_final<<<gROW, blk, 0, stream>>>(S, stats, M, T, scl, (float*)d_out);
}

// Round 6
// 215.350 us; speedup vs baseline: 15.4040x; 1.0778x over previous
//
#include <hip/hip_runtime.h>
#include <hip/hip_bf16.h>

// Problem constants
#define Bn 4
#define Hn 512
#define Wn 512
#define Cn 16
#define Sn 10
#define HWn (Hn*Wn)          // 262144 = 1<<18
#define BHW (Bn*HWn)         // 1048576
#define NG (BHW/4)           // pixel-groups for conv0 (4 px/thread)

// Load 6 consecutive row floats (w0-1 .. w0+4) with boundary zeros. (conv0 only)
__device__ __forceinline__ void load_row6(const float* __restrict__ rp, bool valid,
                                          int w0, float* r) {
    if (valid) {
        float4 v = *reinterpret_cast<const float4*>(rp + w0);
        r[1] = v.x; r[2] = v.y; r[3] = v.z; r[4] = v.w;
        r[0] = (w0 > 0)   ? rp[w0 - 1] : 0.f;
        r[5] = (w0 < 508) ? rp[w0 + 4] : 0.f;
    } else {
        r[0] = r[1] = r[2] = r[3] = r[4] = r[5] = 0.f;
    }
}

// ---------------- conv0: 1->16, 3x3, pad 1, bias; 4 px/thread ----------------
__global__ __launch_bounds__(256) void k_conv0(const float* __restrict__ photos,
        const float* __restrict__ w0v, const float* __restrict__ b0,
        float* __restrict__ out) {
    __shared__ float wp[Cn*12];
    __shared__ float sb[Cn];
    int t = threadIdx.x;
    if (t < Cn*9) { int o = t / 9, k = t % 9; wp[o*12 + k] = w0v[t]; }
    if (t < Cn) sb[t] = b0[t];
    __syncthreads();
    int idx = blockIdx.x * 256 + t;
    int w0 = (idx & 127) << 2, h = (idx >> 7) & 511, b = idx >> 16;
    const float* pb = photos + (b << 18);
    float xr[3][6];
    #pragma unroll
    for (int dy = 0; dy < 3; ++dy) {
        int hh = h + dy - 1;
        load_row6(pb + (hh << 9), (unsigned)hh < 512u, w0, xr[dy]);
    }
    #pragma unroll
    for (int o = 0; o < Cn; ++o) {
        float4 wa = *(const float4*)&wp[o*12];
        float4 wb = *(const float4*)&wp[o*12 + 4];
        float wk8 = wp[o*12 + 8];
        float wk[9] = {wa.x, wa.y, wa.z, wa.w, wb.x, wb.y, wb.z, wb.w, wk8};
        float bv = sb[o];
        float a0 = bv, a1 = bv, a2 = bv, a3 = bv;
        #pragma unroll
        for (int dy = 0; dy < 3; ++dy)
            #pragma unroll
            for (int dx = 0; dx < 3; ++dx) {
                float wv = wk[dy*3 + dx];
                a0 += xr[dy][dx + 0] * wv;
                a1 += xr[dy][dx + 1] * wv;
                a2 += xr[dy][dx + 2] * wv;
                a3 += xr[dy][dx + 3] * wv;
            }
        float4 r; r.x = a0; r.y = a1; r.z = a2; r.w = a3;
        *reinterpret_cast<float4*>(out + ((b*Cn + o) << 18) + (h << 9) + w0) = r;
    }
}

// ====================== LDS-tiled staged conv kernels ======================
// Tile: 128 w x 8 h outputs per block, 256 threads; tw=t&31 (4 px), th=t>>5.
// Per channel: stage 10x128 body + 2x10 halo cols, double-buffered (T14 split:
// issue global loads early, ds_write late, one sync per channel).

struct StageRegs { float4 b0, b1; float hl, hr; };

__device__ __forceinline__ StageRegs stage_load(const float* __restrict__ xc,
                                                int w0, int h0, int t) {
    StageRegs r;
    {   // segment 0: s = t (rows 0..7 of tile)
        int row = t >> 5, c4 = t & 31;
        int gh = h0 - 1 + row;
        r.b0 = make_float4(0.f, 0.f, 0.f, 0.f);
        if ((unsigned)gh < 512u)
            r.b0 = *reinterpret_cast<const float4*>(xc + (gh << 9) + w0 + (c4 << 2));
    }
    r.b1 = make_float4(0.f, 0.f, 0.f, 0.f);
    if (t < 64) {   // segment 1: s = t+256 (rows 8,9)
        int s = t + 256;
        int row = s >> 5, c4 = s & 31;
        int gh = h0 - 1 + row;
        if ((unsigned)gh < 512u)
            r.b1 = *reinterpret_cast<const float4*>(xc + (gh << 9) + w0 + (c4 << 2));
    }
    r.hl = 0.f; r.hr = 0.f;
    if (t < 10) {
        int gh = h0 - 1 + t;
        if (w0 > 0 && (unsigned)gh < 512u) r.hl = xc[(gh << 9) + w0 - 1];
    }
    if (t >= 32 && t < 42) {
        int gh = h0 - 1 + (t - 32);
        if (w0 + 128 < 512 && (unsigned)gh < 512u) r.hr = xc[(gh << 9) + w0 + 128];
    }
    return r;
}

__device__ __forceinline__ void stage_write(float (*tile)[128], float* hL, float* hR,
                                            const StageRegs& r, int t) {
    *reinterpret_cast<float4*>(&tile[t >> 5][(t & 31) << 2]) = r.b0;
    if (t < 64) {
        int s = t + 256;
        *reinterpret_cast<float4*>(&tile[s >> 5][(s & 31) << 2]) = r.b1;
    }
    if (t < 10) hL[t] = r.hl;
    if (t >= 32 && t < 42) hR[t - 32] = r.hr;
}

// Build the three 6-wide rows for this thread from the staged tile.
#define READ_ROWS(tilebuf, hLbuf, hRbuf)                                        \
    float4 v_[3]; float lft_[3], rgt_[3];                                       \
    _Pragma("unroll")                                                           \
    for (int dy = 0; dy < 3; ++dy) {                                            \
        v_[dy] = *reinterpret_cast<const float4*>(&(tilebuf)[th + dy][tw << 2]);\
        float l_ = __shfl_up(v_[dy].w, 1);                                      \
        if (tw == 0) l_ = (hLbuf)[th + dy];                                     \
        float rr_ = __shfl_down(v_[dy].x, 1);                                   \
        if (tw == 31) rr_ = (hRbuf)[th + dy];                                   \
        lft_[dy] = l_; rgt_[dy] = rr_;                                          \
    }

// ------ inverted residual (dw3x3+bn+relu6+pw1x1+bn+skip), staged ------
__global__ __launch_bounds__(256) void k_ir(const float* __restrict__ x,
        float* __restrict__ y, const float* __restrict__ dww,
        const float* __restrict__ as_, const float* __restrict__ ab_,
        const float* __restrict__ pww, const float* __restrict__ bs_,
        const float* __restrict__ bb_) {
    __shared__ float tile[2][10][128];
    __shared__ float hLs[2][10], hRs[2][10];
    __shared__ float dwp[Cn*12];
    __shared__ float pwT[Cn*Cn];   // pwT[i*16+o] = pw[o][i]
    __shared__ float sas[Cn], sab[Cn], sbs[Cn], sbb[Cn];
    int t = threadIdx.x;
    // pwT: Cn*Cn == 256 == blockDim -> exactly one entry per thread (BUGFIX:
    // previous version offset by 32 and never staged entries 224..255).
    { int o = t >> 4, i = t & 15; pwT[i*16 + o] = pww[t]; }
    if (t < Cn*9)  { int c = t / 9, k = t % 9; dwp[c*12 + k] = dww[t]; }
    if (t < Cn) { sas[t] = as_[t]; sab[t] = ab_[t]; }
    if (t >= 64 && t < 64 + Cn) { sbs[t-64] = bs_[t-64]; sbb[t-64] = bb_[t-64]; }

    int bx = blockIdx.x;
    int wt = bx & 3, ht = (bx >> 2) & 63, b = bx >> 8;
    int w0 = wt << 7, h0 = ht << 3;
    int tw = t & 31, th = t >> 5;
    const float* xb = x + ((size_t)b << 22);

    float acc[Cn][4];
    #pragma unroll
    for (int o = 0; o < Cn; ++o) { acc[o][0] = acc[o][1] = acc[o][2] = acc[o][3] = 0.f; }

    // prologue: stage channel 0
    StageRegs sr = stage_load(xb, w0, h0, t);
    stage_write(tile[0], hLs[0], hRs[0], sr, t);
    __syncthreads();

    #pragma unroll 1
    for (int c = 0; c < Cn; ++c) {
        if (c + 1 < Cn) sr = stage_load(xb + ((c + 1) << 18), w0, h0, t);
        int bf = c & 1;
        READ_ROWS(tile[bf], hLs[bf], hRs[bf]);
        // depthwise 3x3
        float4 wa = *(const float4*)&dwp[c*12];
        float4 wb = *(const float4*)&dwp[c*12 + 4];
        float wk8 = dwp[c*12 + 8];
        float wk[9] = {wa.x, wa.y, wa.z, wa.w, wb.x, wb.y, wb.z, wb.w, wk8};
        float t0 = 0.f, t1 = 0.f, t2 = 0.f, t3 = 0.f;
        #pragma unroll
        for (int dy = 0; dy < 3; ++dy) {
            float r6[6] = {lft_[dy], v_[dy].x, v_[dy].y, v_[dy].z, v_[dy].w, rgt_[dy]};
            #pragma unroll
            for (int dx = 0; dx < 3; ++dx) {
                float wv = wk[dy*3 + dx];
                t0 += r6[dx + 0] * wv;
                t1 += r6[dx + 1] * wv;
                t2 += r6[dx + 2] * wv;
                t3 += r6[dx + 3] * wv;
            }
        }
        float sc = sas[c], sh = sab[c];
        t0 = fminf(fmaxf(t0*sc + sh, 0.f), 6.f);
        t1 = fminf(fmaxf(t1*sc + sh, 0.f), 6.f);
        t2 = fminf(fmaxf(t2*sc + sh, 0.f), 6.f);
        t3 = fminf(fmaxf(t3*sc + sh, 0.f), 6.f);
        // pointwise accumulate into all 16 outputs
        #pragma unroll
        for (int o4 = 0; o4 < 4; ++o4) {
            float4 wq = *(const float4*)&pwT[c*16 + o4*4];
            acc[o4*4+0][0] += t0*wq.x; acc[o4*4+0][1] += t1*wq.x;
            acc[o4*4+0][2] += t2*wq.x; acc[o4*4+0][3] += t3*wq.x;
            acc[o4*4+1][0] += t0*wq.y; acc[o4*4+1][1] += t1*wq.y;
            acc[o4*4+1][2] += t2*wq.y; acc[o4*4+1][3] += t3*wq.y;
            acc[o4*4+2][0] += t0*wq.z; acc[o4*4+2][1] += t1*wq.z;
            acc[o4*4+2][2] += t2*wq.z; acc[o4*4+2][3] += t3*wq.z;
            acc[o4*4+3][0] += t0*wq.w; acc[o4*4+3][1] += t1*wq.w;
            acc[o4*4+3][2] += t2*wq.w; acc[o4*4+3][3] += t3*wq.w;
        }
        if (c + 1 < Cn) {
            int nb = (c + 1) & 1;
            stage_write(tile[nb], hLs[nb], hRs[nb], sr, t);
            __syncthreads();
        }
    }
    int h = h0 + th, wg = w0 + (tw << 2);
    #pragma unroll
    for (int o = 0; o < Cn; ++o) {
        const float* xo = xb + (o << 18) + (h << 9) + wg;
        float4 xv = *(const float4*)xo;   // L2-hot residual re-read
        float sc = sbs[o], sh = sbb[o];
        float4 r;
        r.x = xv.x + acc[o][0]*sc + sh;
        r.y = xv.y + acc[o][1]*sc + sh;
        r.z = xv.z + acc[o][2]*sc + sh;
        r.w = xv.w + acc[o][3]*sc + sh;
        *reinterpret_cast<float4*>(y + ((size_t)b << 22) + (o << 18) + (h << 9) + wg) = r;
    }
}

// ------ score conv 16->10, staged ------
__global__ __launch_bounds__(256) void k_convs(const float* __restrict__ x,
        const float* __restrict__ wsw, const float* __restrict__ bsv,
        float* __restrict__ s) {
    __shared__ float tile[2][10][128];
    __shared__ float hLs[2][10], hRs[2][10];
    __shared__ float wp[Cn*Sn*12];   // wp[(c*10+o)*12+k]
    __shared__ float sb[Sn];
    int t = threadIdx.x;
    for (int i = t; i < Sn*Cn*9; i += 256) {
        int o = i / (Cn*9), r = i % (Cn*9), c = r / 9, k = r % 9;
        wp[(c*Sn + o)*12 + k] = wsw[i];
    }
    if (t < Sn) sb[t] = bsv[t];

    int bx = blockIdx.x;
    int wt = bx & 3, ht = (bx >> 2) & 63, b = bx >> 8;
    int w0 = wt << 7, h0 = ht << 3;
    int tw = t & 31, th = t >> 5;
    const float* xb = x + ((size_t)b << 22);

    float acc[Sn][4];
    #pragma unroll
    for (int o = 0; o < Sn; ++o) {
        float bv = bsv[o];
        acc[o][0] = bv; acc[o][1] = bv; acc[o][2] = bv; acc[o][3] = bv;
    }

    StageRegs sr = stage_load(xb, w0, h0, t);
    stage_write(tile[0], hLs[0], hRs[0], sr, t);
    __syncthreads();

    #pragma unroll 1
    for (int c = 0; c < Cn; ++c) {
        if (c + 1 < Cn) sr = stage_load(xb + ((c + 1) << 18), w0, h0, t);
        int bf = c & 1;
        READ_ROWS(tile[bf], hLs[bf], hRs[bf]);
        #pragma unroll
        for (int o = 0; o < Sn; ++o) {
            const float* wb_ = &wp[(c*Sn + o)*12];
            float4 wa = *(const float4*)wb_;
            float4 wv2 = *(const float4*)(wb_ + 4);
            float wk8 = wb_[8];
            float wk[9] = {wa.x, wa.y, wa.z, wa.w, wv2.x, wv2.y, wv2.z, wv2.w, wk8};
            #pragma unroll
            for (int dy = 0; dy < 3; ++dy) {
                float r6[6] = {lft_[dy], v_[dy].x, v_[dy].y, v_[dy].z, v_[dy].w, rgt_[dy]};
                #pragma unroll
                for (int dx = 0; dx < 3; ++dx) {
                    float wv = wk[dy*3 + dx];
                    acc[o][0] += r6[dx + 0] * wv;
                    acc[o][1] += r6[dx + 1] * wv;
                    acc[o][2] += r6[dx + 2] * wv;
                    acc[o][3] += r6[dx + 3] * wv;
                }
            }
        }
        if (c + 1 < Cn) {
            int nb = (c + 1) & 1;
            stage_write(tile[nb], hLs[nb], hRs[nb], sr, t);
            __syncthreads();
        }
    }
    int h = h0 + th, wg = w0 + (tw << 2);
    #pragma unroll
    for (int o = 0; o < Sn; ++o) {
        float4 r; r.x = acc[o][0]; r.y = acc[o][1]; r.z = acc[o][2]; r.w = acc[o][3];
        *reinterpret_cast<float4*>(s + ((b*Sn + o) << 18) + (h << 9) + wg) = r;
    }
}

// ---------------- instance norm stage 1: partial sums (32 chunks/plane) ----------
__global__ __launch_bounds__(256) void k_in_part(const float* __restrict__ s,
                                                 double* __restrict__ part) {
    int bc = blockIdx.x >> 5, ch = blockIdx.x & 31;
    const float4* p4 = (const float4*)(s + ((size_t)bc << 18) + (ch << 13));
    int t = threadIdx.x;
    double sum = 0.0, sq = 0.0;
    #pragma unroll
    for (int i = 0; i < 8; ++i) {
        float4 v = p4[t + i * 256];
        sum += (double)v.x + (double)v.y + (double)v.z + (double)v.w;
        sq  += (double)v.x*v.x + (double)v.y*v.y + (double)v.z*v.z + (double)v.w*v.w;
    }
    __shared__ double ssum[256], ssq[256];
    ssum[t] = sum; ssq[t] = sq;
    __syncthreads();
    for (int off = 128; off > 0; off >>= 1) {
        if (t < off) { ssum[t] += ssum[t + off]; ssq[t] += ssq[t + off]; }
        __syncthreads();
    }
    if (t == 0) {
        part[blockIdx.x * 2]     = ssum[0];
        part[blockIdx.x * 2 + 1] = ssq[0];
    }
}

// ---------------- instance norm stage 2: finalize {mu, rsqrt} ----------------
__global__ __launch_bounds__(64) void k_in_fin(const double* __restrict__ part,
                                               float2* __restrict__ stats) {
    int bc = blockIdx.x;
    int t = threadIdx.x;
    double sum = 0.0, sq = 0.0;
    if (t < 32) { sum = part[(bc * 32 + t) * 2]; sq = part[(bc * 32 + t) * 2 + 1]; }
    #pragma unroll
    for (int off = 32; off > 0; off >>= 1) {
        sum += __shfl_xor(sum, off);
        sq  += __shfl_xor(sq, off);
    }
    if (t == 0) {
        double mu = sum / (double)HWn;
        double var = sq / (double)HWn - mu * mu;
        float2 st; st.x = (float)mu; st.y = rsqrtf((float)var + 1e-5f);
        stats[bc] = st;
    }
}

// norm + leaky-relu applied on the fly (S stays raw everywhere)
__device__ __forceinline__ float nrm(float v, float2 st) {
    float r = (v - st.x) * st.y;
    return r >= 0.f ? r : 0.01f * r;
}

// ---- R1: chanmax + rowmax. One block per (b,h) row; 2 px/thread. ----
__global__ __launch_bounds__(256) void k_chan_rowmax(const float* __restrict__ s,
        const float2* __restrict__ stats, float* __restrict__ m1) {
    __shared__ float rowbuf[512];
    int bh = blockIdx.x;
    int b = bh >> 9, h = bh & 511;
    int t = threadIdx.x, w0 = t << 1;
    const float* sp = s + ((size_t)(b * Sn) << 18) + (h << 9) + w0;
    float mx0 = -INFINITY, mx1 = -INFINITY;
    #pragma unroll
    for (int c = 0; c < Sn; ++c) {
        float2 st = stats[b * Sn + c];
        float2 v = *reinterpret_cast<const float2*>(sp + ((size_t)c << 18));
        mx0 = fmaxf(mx0, nrm(v.x, st));
        mx1 = fmaxf(mx1, nrm(v.y, st));
    }
    rowbuf[w0] = mx0; rowbuf[w0 + 1] = mx1;
    __syncthreads();
    float2 o;
    {
        int lo = max(w0 - 7, 0), hi = min(w0 + 7, 511);
        float m = -INFINITY;
        for (int ww = lo; ww <= hi; ++ww) m = fmaxf(m, rowbuf[ww]);
        o.x = m;
        int w1 = w0 + 1;
        lo = max(w1 - 7, 0); hi = min(w1 + 7, 511);
        m = -INFINITY;
        for (int ww = lo; ww <= hi; ++ww) m = fmaxf(m, rowbuf[ww]);
        o.y = m;
    }
    *reinterpret_cast<float2*>(m1 + (bh << 9) + w0) = o;
}

// ---- R2: colmax -> M, expsum, rowsum -> T. One block per (b,h) row. ----
__global__ __launch_bounds__(256) void k_col_expsum(const float* __restrict__ s,
        const float2* __restrict__ stats, const float* __restrict__ m1,
        float* __restrict__ mfull, float* __restrict__ tout) {
    __shared__ float esbuf[512];
    int bh = blockIdx.x;
    int b = bh >> 9, h = bh & 511;
    int t = threadIdx.x, w0 = t << 1;
    int lo = max(h - 7, 0), hi = min(h + 7, 511);
    float2 m = make_float2(-INFINITY, -INFINITY);
    for (int hh = lo; hh <= hi; ++hh) {
        float2 v = *reinterpret_cast<const float2*>(m1 + ((size_t)b << 18) + (hh << 9) + w0);
        m.x = fmaxf(m.x, v.x); m.y = fmaxf(m.y, v.y);
    }
    *reinterpret_cast<float2*>(mfull + (bh << 9) + w0) = m;
    const float* sp = s + ((size_t)(b * Sn) << 18) + (h << 9) + w0;
    float es0 = 0.f, es1 = 0.f;
    #pragma unroll
    for (int c = 0; c < Sn; ++c) {
        float2 st = stats[b * Sn + c];
        float2 v = *reinterpret_cast<const float2*>(sp + ((size_t)c << 18));
        es0 += __expf(7.f * (nrm(v.x, st) - m.x));
        es1 += __expf(7.f * (nrm(v.y, st) - m.y));
    }
    esbuf[w0] = es0; esbuf[w0 + 1] = es1;
    __syncthreads();
    float2 o;
    {
        int wlo = max(w0 - 7, 0), whi = min(w0 + 7, 511);
        float a = 0.f;
        for (int ww = wlo; ww <= whi; ++ww) a += esbuf[ww];
        o.x = a;
        int w1 = w0 + 1;
        wlo = max(w1 - 7, 0); whi = min(w1 + 7, 511);
        a = 0.f;
        for (int ww = wlo; ww <= whi; ++ww) a += esbuf[ww];
        o.y = a;
    }
    *reinterpret_cast<float2*>(tout + (bh << 9) + w0) = o;
}

// ---- R3: colsum -> SU, channel softmax, outputs. One block per (b,h) row. ----
__global__ __launch_bounds__(256) void k_final(const float* __restrict__ s,
        const float2* __restrict__ stats, const float* __restrict__ mfull,
        const float* __restrict__ tin, const float* __restrict__ scl,
        float* __restrict__ out) {
    __shared__ float sscale[Sn];
    int t = threadIdx.x;
    if (t < Sn) sscale[t] = scl[t];
    __syncthreads();
    int bh = blockIdx.x;
    int b = bh >> 9, h = bh & 511;
    int w0 = t << 1;
    int lo = max(h - 7, 0), hi = min(h + 7, 511);
    float2 su = make_float2(0.f, 0.f);
    for (int hh = lo; hh <= hi; ++hh) {
        float2 v = *reinterpret_cast<const float2*>(tin + ((size_t)b << 18) + (hh << 9) + w0);
        su.x += v.x; su.y += v.y;
    }
    float2 m = *reinterpret_cast<const float2*>(mfull + (bh << 9) + w0);
    float d0 = 1.f / (su.x + 1e-8f), d1i = 1.f / (su.y + 1e-8f);
    const float* sp = s + ((size_t)(b * Sn) << 18) + (h << 9) + w0;
    float pr0[Sn], pr1[Sn];
    float mx0 = -INFINITY, mx1 = -INFINITY;
    #pragma unroll
    for (int c = 0; c < Sn; ++c) {
        float2 st = stats[b * Sn + c];
        float2 v = *reinterpret_cast<const float2*>(sp + ((size_t)c << 18));
        float p0 = expf(7.f * (nrm(v.x, st) - m.x)) * d0;
        float p1 = expf(7.f * (nrm(v.y, st) - m.y)) * d1i;
        pr0[c] = p0; pr1[c] = p1;
        mx0 = fmaxf(mx0, p0); mx1 = fmaxf(mx1, p1);
    }
    float e0[Sn], e1[Sn];
    float s0 = 0.f, s1 = 0.f;
    #pragma unroll
    for (int c = 0; c < Sn; ++c) {
        e0[c] = expf(100.f * (pr0[c] - mx0)); s0 += e0[c];
        e1[c] = expf(100.f * (pr1[c] - mx1)); s1 += e1[c];
    }
    float i0 = 1.f / (s0 + 1e-8f), i1 = 1.f / (s1 + 1e-8f);
    float sc0 = 0.f, sc1 = 0.f, sl0 = 0.f, sl1 = 0.f;
    #pragma unroll
    for (int c = 0; c < Sn; ++c) {
        float p0 = e0[c] * i0, p1 = e1[c] * i1;
        sc0 += pr0[c] * p0; sl0 += sscale[c] * p0;
        sc1 += pr1[c] * p1; sl1 += sscale[c] * p1;
    }
    int oi = (bh << 9) + w0;
    float2 r0; r0.x = sc0; r0.y = sc1;
    float2 r1; r1.x = sl0; r1.y = sl1;
    *reinterpret_cast<float2*>(out + oi) = r0;
    *reinterpret_cast<float2*>(out + BHW + oi) = r1;
}

extern "C" void kernel_launch(void* const* d_in, const int* in_sizes, int n_in,
                              void* d_out, int out_size, void* d_ws, size_t ws_size,
                              hipStream_t stream) {
    const float* photos = (const float*)d_in[0];
    const float* w0     = (const float*)d_in[1];
    const float* b0     = (const float*)d_in[2];
    const float* dw1_w  = (const float*)d_in[3];
    const float* bn1a_s = (const float*)d_in[4];
    const float* bn1a_b = (const float*)d_in[5];
    const float* pw1_w  = (const float*)d_in[6];
    const float* bn1b_s = (const float*)d_in[7];
    const float* bn1b_b = (const float*)d_in[8];
    const float* dw2_w  = (const float*)d_in[9];
    const float* bn2a_s = (const float*)d_in[10];
    const float* bn2a_b = (const float*)d_in[11];
    const float* pw2_w  = (const float*)d_in[12];
    const float* bn2b_s = (const float*)d_in[13];
    const float* bn2b_b = (const float*)d_in[14];
    const float* ws_w   = (const float*)d_in[15];
    const float* bs_v   = (const float*)d_in[16];
    const float* scl    = (const float*)d_in[17];

    char* wsb = (char*)d_ws;
    float* A  = (float*)(wsb);                         // 64 MiB (B,16,H,W)
    float* Bb = (float*)(wsb + 67108864);              // 64 MiB (B,16,H,W)
    float* S  = (float*)(wsb + 134217728);             // 40 MiB raw conv output
    float2* stats = (float2*)Bb;                       // 40 float2 (Bb dead then)
    double* part  = (double*)(Bb + 1024);              // 1280*2 doubles
    float* M1 = A;                                     // 4 MiB each (A dead then)
    float* M  = A + 1 * (1 << 20);
    float* T  = A + 2 * (1 << 20);

    dim3 blk(256);
    int gNG   = NG / 256;             // 1024 blocks (conv0, 4 px/thread)
    int gTILE = 4 * 64 * Bn;          // 1024 tile blocks (128x8 per block)
    int gROW  = Bn * Hn;              // 2048 row-blocks

    k_conv0<<<gNG, blk, 0, stream>>>(photos, w0, b0, A);
    k_ir<<<gTILE, blk, 0, stream>>>(A, Bb, dw1_w, bn1a_s, bn1a_b, pw1_w, bn1b_s, bn1b_b);
    k_ir<<<gTILE, blk, 0, stream>>>(Bb, A, dw2_w, bn2a_s, bn2a_b, pw2_w, bn2b_s, bn2b_b);
    k_convs<<<gTILE, blk, 0, stream>>>(A, ws_w, bs_v, S);
    k_in_part<<<Bn * Sn * 32, blk, 0, stream>>>(S, part);
    k_in_fin<<<Bn * Sn, dim3(64), 0, stream>>>(part, stats);
    k_chan_rowmax<<<gROW, blk, 0, stream>>>(S, stats, M1);
    k_col_expsum<<<gROW, blk, 0, stream>>>(S, stats, M1, M, T);
    k_final<<<gROW, blk, 0, stream>>>(S, stats, M, T, scl, (float*)d_out);
}